// Round 4
// baseline (580.534 us; speedup 1.0000x reference)
//
#include <hip/hip_runtime.h>
#include <math.h>

// ---------------------------------------------------------------------------
// 2-layer GCN (PyG GCNConv semantics) on MI355X.
//   deg[c]  = #incoming edges + 1 (self loop); dinv = rsqrt(deg)
//   g       = bf16( dinv[n] * (X @ W) )     (GEMM + epilogue scale + pack)
//   out[c]  = dinv[c] * (g[c] + sum_{(r,c) in E} g[r]) + b   (CSR gather)
//   layer1: ReLU -> h1 (fp32); layer2: none, writes d_out (fp32).
// CSR built once per call via counting sort; no float atomics anywhere.
// R4: scatter uses cursor pre-initialized to off (one fewer random read +
//     shorter dep chain), 4 edges/thread int4; agg split into 64B channel-line
//     groups keyed on blockIdx%GROUPS for per-XCD L2 locality.
// ---------------------------------------------------------------------------

#define BS 256

__device__ __forceinline__ unsigned pack_bf16x2(float a, float b) {
    unsigned ua = __float_as_uint(a);
    unsigned ub = __float_as_uint(b);
    ua = (ua + 0x7fffu + ((ua >> 16) & 1u)) >> 16;   // RTE
    ub = (ub + 0x7fffu + ((ub >> 16) & 1u)) >> 16;
    return ua | (ub << 16);
}

__device__ __forceinline__ float bf_lo(unsigned u) { return __uint_as_float(u << 16); }
__device__ __forceinline__ float bf_hi(unsigned u) { return __uint_as_float(u & 0xffff0000u); }

__global__ __launch_bounds__(BS) void count_kernel(const int* __restrict__ col,
                                                   int* __restrict__ cnt, int E) {
    int i0 = (blockIdx.x * BS + threadIdx.x) * 4;
    if (i0 + 4 <= E) {
        int4 c4 = *(const int4*)(col + i0);
        atomicAdd(&cnt[c4.x], 1);
        atomicAdd(&cnt[c4.y], 1);
        atomicAdd(&cnt[c4.z], 1);
        atomicAdd(&cnt[c4.w], 1);
    } else {
        for (int i = i0; i < E; ++i) atomicAdd(&cnt[col[i]], 1);
    }
}

__global__ __launch_bounds__(BS) void scan_block_kernel(const int* __restrict__ cnt,
                                                        int* __restrict__ exc,
                                                        int* __restrict__ bsum, int N) {
    __shared__ int s[BS];
    int tid = threadIdx.x;
    int i = blockIdx.x * BS + tid;
    int v = (i < N) ? cnt[i] : 0;
    s[tid] = v;
    __syncthreads();
    for (int off = 1; off < BS; off <<= 1) {
        int t = (tid >= off) ? s[tid - off] : 0;
        __syncthreads();
        s[tid] += t;
        __syncthreads();
    }
    if (i < N) exc[i] = s[tid] - v;       // exclusive within block
    if (tid == BS - 1) bsum[blockIdx.x] = s[BS - 1];
}

__global__ __launch_bounds__(512) void scan_bsum_kernel(const int* __restrict__ bsum,
                                                        int* __restrict__ boff, int NB) {
    __shared__ int s[512];
    int tid = threadIdx.x;
    int v = (tid < NB) ? bsum[tid] : 0;
    s[tid] = v;
    __syncthreads();
    for (int off = 1; off < 512; off <<= 1) {
        int t = (tid >= off) ? s[tid - off] : 0;
        __syncthreads();
        s[tid] += t;
        __syncthreads();
    }
    if (tid < NB) boff[tid] = s[tid] - v; // exclusive across blocks
}

// exc += block offset; cursor = final off; dinv = rsqrt(deg+1)
__global__ __launch_bounds__(BS) void add_off_dinv_kernel(int* __restrict__ exc,
                                                          const int* __restrict__ boff,
                                                          const int* __restrict__ cnt,
                                                          int* __restrict__ cursor,
                                                          float* __restrict__ dinv, int N) {
    int i = blockIdx.x * BS + threadIdx.x;
    if (i < N) {
        int o = exc[i] + boff[blockIdx.x];
        exc[i] = o;
        cursor[i] = o;
        dinv[i] = rsqrtf((float)(cnt[i] + 1));
    }
}

__global__ __launch_bounds__(BS) void scatter_kernel(const int* __restrict__ row,
                                                     const int* __restrict__ col,
                                                     int* __restrict__ cursor,
                                                     int* __restrict__ src, int E) {
    int i0 = (blockIdx.x * BS + threadIdx.x) * 4;
    if (i0 + 4 <= E) {
        int4 c4 = *(const int4*)(col + i0);
        int4 r4 = *(const int4*)(row + i0);
        int p0 = atomicAdd(&cursor[c4.x], 1);
        int p1 = atomicAdd(&cursor[c4.y], 1);
        int p2 = atomicAdd(&cursor[c4.z], 1);
        int p3 = atomicAdd(&cursor[c4.w], 1);
        src[p0] = r4.x;
        src[p1] = r4.y;
        src[p2] = r4.z;
        src[p3] = r4.w;
    } else {
        for (int i = i0; i < E; ++i) {
            int p = atomicAdd(&cursor[col[i]], 1);
            src[p] = row[i];
        }
    }
}

// G[n][COLS] (bf16, packed pairs) = bf16( dinv[n] * (A[n][128] @ W[128][COLS]) )
template <int COLS>
__global__ __launch_bounds__(BS) void gemm_scale_kernel(const float* __restrict__ A,
                                                        const float* __restrict__ W,
                                                        const float* __restrict__ dinv,
                                                        unsigned* __restrict__ G, int n) {
    constexpr int K = 128;
    constexpr int CG = COLS / 4;
    constexpr int RT = BS / CG;
    constexpr int ROWS = RT * 4;
    constexpr int KS = (COLS == 64) ? (K + 4) : K;   // xs row stride (floats)

    __shared__ float ws[K * COLS];
    __shared__ float xs[ROWS * KS];

    int tid = threadIdx.x;
    int r0 = blockIdx.x * ROWS;

    const float4* W4 = (const float4*)W;
    float4* ws4 = (float4*)ws;
    for (int i = tid; i < K * CG; i += BS) ws4[i] = W4[i];

    for (int i = tid; i < ROWS * (K / 4); i += BS) {
        int r = i / (K / 4);
        int kq = i % (K / 4);
        int grow = r0 + r;
        float4 v = make_float4(0.f, 0.f, 0.f, 0.f);
        if (grow < n) v = ((const float4*)A)[(size_t)grow * (K / 4) + kq];
        ((float4*)(xs + r * KS))[kq] = v;
    }
    __syncthreads();

    int cg = tid % CG;
    int rt = tid / CG;
    const float4* xr0 = (const float4*)(xs + (rt * 4 + 0) * KS);
    const float4* xr1 = (const float4*)(xs + (rt * 4 + 1) * KS);
    const float4* xr2 = (const float4*)(xs + (rt * 4 + 2) * KS);
    const float4* xr3 = (const float4*)(xs + (rt * 4 + 3) * KS);

    float4 acc[4];
#pragma unroll
    for (int j = 0; j < 4; ++j) acc[j] = make_float4(0, 0, 0, 0);

#pragma unroll 2
    for (int kq = 0; kq < K / 4; ++kq) {
        float4 a0 = xr0[kq], a1 = xr1[kq], a2 = xr2[kq], a3 = xr3[kq];
        float4 w0 = ws4[(4 * kq + 0) * CG + cg];
        float4 w1 = ws4[(4 * kq + 1) * CG + cg];
        float4 w2 = ws4[(4 * kq + 2) * CG + cg];
        float4 w3 = ws4[(4 * kq + 3) * CG + cg];
#define FMA4(ac, a)                                                            \
        ac.x += a.x * w0.x + a.y * w1.x + a.z * w2.x + a.w * w3.x;             \
        ac.y += a.x * w0.y + a.y * w1.y + a.z * w2.y + a.w * w3.y;             \
        ac.z += a.x * w0.z + a.y * w1.z + a.z * w2.z + a.w * w3.z;             \
        ac.w += a.x * w0.w + a.y * w1.w + a.z * w2.w + a.w * w3.w;
        FMA4(acc[0], a0)
        FMA4(acc[1], a1)
        FMA4(acc[2], a2)
        FMA4(acc[3], a3)
#undef FMA4
    }

#pragma unroll
    for (int j = 0; j < 4; ++j) {
        int grow = r0 + rt * 4 + j;
        if (grow < n) {
            float dv = dinv[grow];
            uint2 o;
            o.x = pack_bf16x2(acc[j].x * dv, acc[j].y * dv);
            o.y = pack_bf16x2(acc[j].z * dv, acc[j].w * dv);
            ((uint2*)(G + (size_t)grow * (COLS / 2)))[cg] = o;
        }
    }
}

// out[node][c] = act( dinv[node] * (G[node][c] + sum_{s} G[s][c]) + b[c] )
// G bf16-packed. Channel-line groups: each block covers one 64B line (32 ch)
// of its nodes, group = blockIdx % GROUPS -> per-XCD L2 footprint shrinks
// under round-robin workgroup dispatch. 8-deep gather MLP.
template <int C, bool RELU>
__global__ __launch_bounds__(BS) void agg_kernel(const unsigned* __restrict__ G,
                                                 const int* __restrict__ edge_off,
                                                 const int* __restrict__ cnt,
                                                 const int* __restrict__ src,
                                                 const float* __restrict__ dinv,
                                                 const float* __restrict__ bias,
                                                 float* __restrict__ out, int n) {
    constexpr int RQ = C / 8;              // uint4 per G row
    constexpr int GROUPS = RQ / 4;         // 64B line groups per row
    constexpr int Gp = 4;                  // lanes per node (4 x uint4 = 32 ch)
    constexpr int NPB = BS / Gp;           // nodes per block

    int group = blockIdx.x % GROUPS;
    int nb = blockIdx.x / GROUPS;
    int lane = threadIdx.x % Gp;
    int li = threadIdx.x / Gp;
    int node = nb * NPB + li;
    if (node >= n) return;
    int qi = group * 4 + lane;             // uint4 index within row

    const uint4* G4 = (const uint4*)G;
    float acc[8];
    {
        uint4 sv = G4[(size_t)node * RQ + qi];   // self-loop term
        acc[0] = bf_lo(sv.x); acc[1] = bf_hi(sv.x);
        acc[2] = bf_lo(sv.y); acc[3] = bf_hi(sv.y);
        acc[4] = bf_lo(sv.z); acc[5] = bf_hi(sv.z);
        acc[6] = bf_lo(sv.w); acc[7] = bf_hi(sv.w);
    }
    const int* sp = src + edge_off[node];
    int deg = cnt[node];

#define ACCUM(v)                                                               \
    acc[0] += bf_lo(v.x); acc[1] += bf_hi(v.x);                                \
    acc[2] += bf_lo(v.y); acc[3] += bf_hi(v.y);                                \
    acc[4] += bf_lo(v.z); acc[5] += bf_hi(v.z);                                \
    acc[6] += bf_lo(v.w); acc[7] += bf_hi(v.w);

    int i = 0;
    for (; i + 8 <= deg; i += 8) {
        int s0 = sp[i + 0], s1 = sp[i + 1], s2 = sp[i + 2], s3 = sp[i + 3];
        int s4 = sp[i + 4], s5 = sp[i + 5], s6 = sp[i + 6], s7 = sp[i + 7];
        uint4 v0 = G4[(size_t)s0 * RQ + qi];
        uint4 v1 = G4[(size_t)s1 * RQ + qi];
        uint4 v2 = G4[(size_t)s2 * RQ + qi];
        uint4 v3 = G4[(size_t)s3 * RQ + qi];
        uint4 v4 = G4[(size_t)s4 * RQ + qi];
        uint4 v5 = G4[(size_t)s5 * RQ + qi];
        uint4 v6 = G4[(size_t)s6 * RQ + qi];
        uint4 v7 = G4[(size_t)s7 * RQ + qi];
        ACCUM(v0) ACCUM(v1) ACCUM(v2) ACCUM(v3)
        ACCUM(v4) ACCUM(v5) ACCUM(v6) ACCUM(v7)
    }
    for (; i + 2 <= deg; i += 2) {
        int s0 = sp[i + 0], s1 = sp[i + 1];
        uint4 v0 = G4[(size_t)s0 * RQ + qi];
        uint4 v1 = G4[(size_t)s1 * RQ + qi];
        ACCUM(v0) ACCUM(v1)
    }
    if (i < deg) {
        uint4 v0 = G4[(size_t)sp[i] * RQ + qi];
        ACCUM(v0)
    }
#undef ACCUM

    float dv = dinv[node];
    const float4* b4 = (const float4*)bias;
    float4 bl = b4[2 * qi + 0], bh = b4[2 * qi + 1];
    float4 o0 = make_float4(acc[0] * dv + bl.x, acc[1] * dv + bl.y,
                            acc[2] * dv + bl.z, acc[3] * dv + bl.w);
    float4 o1 = make_float4(acc[4] * dv + bh.x, acc[5] * dv + bh.y,
                            acc[6] * dv + bh.z, acc[7] * dv + bh.w);
    if (RELU) {
        o0.x = fmaxf(o0.x, 0.f); o0.y = fmaxf(o0.y, 0.f);
        o0.z = fmaxf(o0.z, 0.f); o0.w = fmaxf(o0.w, 0.f);
        o1.x = fmaxf(o1.x, 0.f); o1.y = fmaxf(o1.y, 0.f);
        o1.z = fmaxf(o1.z, 0.f); o1.w = fmaxf(o1.w, 0.f);
    }
    float4* orow = (float4*)(out + (size_t)node * C);
    orow[2 * qi + 0] = o0;
    orow[2 * qi + 1] = o1;
}

extern "C" void kernel_launch(void* const* d_in, const int* in_sizes, int n_in,
                              void* d_out, int out_size, void* d_ws, size_t ws_size,
                              hipStream_t stream) {
    const float* x  = (const float*)d_in[0];
    const int*   ei = (const int*)d_in[1];      // [2, E] int32
    const float* W1 = (const float*)d_in[2];
    const float* b1 = (const float*)d_in[3];
    const float* W2 = (const float*)d_in[4];
    const float* b2 = (const float*)d_in[5];

    const int IN_C = 128, HID_C = 128;
    int n = in_sizes[0] / IN_C;
    int E = in_sizes[1] / 2;
    const int* row = ei;
    const int* col = ei + E;

    int NB = (n + BS - 1) / BS;

    char* w = (char*)d_ws;
    auto alloc = [&](size_t bytes) {
        void* p = (void*)w;
        w += (bytes + 255) & ~(size_t)255;
        return p;
    };
    int*      cnt    = (int*)alloc((size_t)n * 4);
    int*      off    = (int*)alloc((size_t)n * 4);
    int*      cursor = (int*)alloc((size_t)n * 4);
    int*      bsum   = (int*)alloc((size_t)NB * 4);
    int*      boff   = (int*)alloc((size_t)NB * 4);
    int*      src    = (int*)alloc((size_t)E * 4);
    float*    dinv   = (float*)alloc((size_t)n * 4);
    unsigned* g      = (unsigned*)alloc((size_t)n * HID_C * 2);  // bf16-packed
    float*    h1     = (float*)alloc((size_t)n * HID_C * 4);

    hipMemsetAsync(cnt, 0, (size_t)n * 4, stream);

    int gridE4 = ((E + 3) / 4 + BS - 1) / BS;

    // degree + CSR build
    count_kernel<<<gridE4, BS, 0, stream>>>(col, cnt, E);
    scan_block_kernel<<<NB, BS, 0, stream>>>(cnt, off, bsum, n);
    scan_bsum_kernel<<<1, 512, 0, stream>>>(bsum, boff, NB);
    add_off_dinv_kernel<<<NB, BS, 0, stream>>>(off, boff, cnt, cursor, dinv, n);
    scatter_kernel<<<gridE4, BS, 0, stream>>>(row, col, cursor, src, E);

    // layer 1: g1 = bf16(dinv * (x @ W1)); h1 = relu(dinv*(self + gather) + b1)
    gemm_scale_kernel<128><<<(n + 31) / 32, BS, 0, stream>>>(x, W1, dinv, g, n);
    {
        int nodeBlocks = (n + 63) / 64;           // NPB=64
        agg_kernel<128, true><<<nodeBlocks * 4, BS, 0, stream>>>(g, off, cnt, src,
                                                                 dinv, b1, h1, n);
    }

    // layer 2: g2 = bf16(dinv * (h1 @ W2)); out = dinv*(self + gather) + b2
    gemm_scale_kernel<64><<<(n + 63) / 64, BS, 0, stream>>>(h1, W2, dinv, g, n);
    {
        int nodeBlocks = (n + 63) / 64;           // NPB=64
        agg_kernel<64, false><<<nodeBlocks * 2, BS, 0, stream>>>(g, off, cnt, src,
                                                                 dinv, b2,
                                                                 (float*)d_out, n);
    }
}

// Round 5
// 499.703 us; speedup vs baseline: 1.1618x; 1.1618x over previous
//
#include <hip/hip_runtime.h>
#include <math.h>

// ---------------------------------------------------------------------------
// 2-layer GCN (PyG GCNConv semantics) on MI355X.
//   deg[c]  = #incoming edges + 1 (self loop); dinv = rsqrt(deg)
//   g       = bf16( dinv[n] * (X @ W) )     (GEMM + epilogue scale + pack)
//   out[c]  = dinv[c] * (g[c] + sum_{(r,c) in E} g[r]) + b   (CSR gather)
//   layer1: ReLU -> h1 (fp32); layer2: none, writes d_out (fp32).
// CSR built once per call via counting sort; no float atomics anywhere.
// R5: revert R4's 4-edge/thread scatter (occupancy 72->45%, serialized atomic
//     chains) and agg channel-grouping (re-read src list per group = extra
//     latency-bound traffic). Keep cursor-preinit (single random atomic/edge,
//     verified FETCH 8.1->6.6MB).
// ---------------------------------------------------------------------------

#define BS 256

__device__ __forceinline__ unsigned pack_bf16x2(float a, float b) {
    unsigned ua = __float_as_uint(a);
    unsigned ub = __float_as_uint(b);
    ua = (ua + 0x7fffu + ((ua >> 16) & 1u)) >> 16;   // RTE
    ub = (ub + 0x7fffu + ((ub >> 16) & 1u)) >> 16;
    return ua | (ub << 16);
}

__device__ __forceinline__ float bf_lo(unsigned u) { return __uint_as_float(u << 16); }
__device__ __forceinline__ float bf_hi(unsigned u) { return __uint_as_float(u & 0xffff0000u); }

__global__ __launch_bounds__(BS) void count_kernel(const int* __restrict__ col,
                                                   int* __restrict__ cnt, int E) {
    int i = blockIdx.x * BS + threadIdx.x;
    if (i < E) atomicAdd(&cnt[col[i]], 1);
}

__global__ __launch_bounds__(BS) void scan_block_kernel(const int* __restrict__ cnt,
                                                        int* __restrict__ exc,
                                                        int* __restrict__ bsum, int N) {
    __shared__ int s[BS];
    int tid = threadIdx.x;
    int i = blockIdx.x * BS + tid;
    int v = (i < N) ? cnt[i] : 0;
    s[tid] = v;
    __syncthreads();
    for (int off = 1; off < BS; off <<= 1) {
        int t = (tid >= off) ? s[tid - off] : 0;
        __syncthreads();
        s[tid] += t;
        __syncthreads();
    }
    if (i < N) exc[i] = s[tid] - v;       // exclusive within block
    if (tid == BS - 1) bsum[blockIdx.x] = s[BS - 1];
}

__global__ __launch_bounds__(512) void scan_bsum_kernel(const int* __restrict__ bsum,
                                                        int* __restrict__ boff, int NB) {
    __shared__ int s[512];
    int tid = threadIdx.x;
    int v = (tid < NB) ? bsum[tid] : 0;
    s[tid] = v;
    __syncthreads();
    for (int off = 1; off < 512; off <<= 1) {
        int t = (tid >= off) ? s[tid - off] : 0;
        __syncthreads();
        s[tid] += t;
        __syncthreads();
    }
    if (tid < NB) boff[tid] = s[tid] - v; // exclusive across blocks
}

// exc += block offset; cursor = final off; dinv = rsqrt(deg+1)
__global__ __launch_bounds__(BS) void add_off_dinv_kernel(int* __restrict__ exc,
                                                          const int* __restrict__ boff,
                                                          const int* __restrict__ cnt,
                                                          int* __restrict__ cursor,
                                                          float* __restrict__ dinv, int N) {
    int i = blockIdx.x * BS + threadIdx.x;
    if (i < N) {
        int o = exc[i] + boff[blockIdx.x];
        exc[i] = o;
        cursor[i] = o;
        dinv[i] = rsqrtf((float)(cnt[i] + 1));
    }
}

__global__ __launch_bounds__(BS) void scatter_kernel(const int* __restrict__ row,
                                                     const int* __restrict__ col,
                                                     int* __restrict__ cursor,
                                                     int* __restrict__ src, int E) {
    int i = blockIdx.x * BS + threadIdx.x;
    if (i >= E) return;
    int p = atomicAdd(&cursor[col[i]], 1);
    src[p] = row[i];
}

// G[n][COLS] (bf16, packed pairs) = bf16( dinv[n] * (A[n][128] @ W[128][COLS]) )
template <int COLS>
__global__ __launch_bounds__(BS) void gemm_scale_kernel(const float* __restrict__ A,
                                                        const float* __restrict__ W,
                                                        const float* __restrict__ dinv,
                                                        unsigned* __restrict__ G, int n) {
    constexpr int K = 128;
    constexpr int CG = COLS / 4;
    constexpr int RT = BS / CG;
    constexpr int ROWS = RT * 4;
    constexpr int KS = (COLS == 64) ? (K + 4) : K;   // xs row stride (floats)

    __shared__ float ws[K * COLS];
    __shared__ float xs[ROWS * KS];

    int tid = threadIdx.x;
    int r0 = blockIdx.x * ROWS;

    const float4* W4 = (const float4*)W;
    float4* ws4 = (float4*)ws;
    for (int i = tid; i < K * CG; i += BS) ws4[i] = W4[i];

    for (int i = tid; i < ROWS * (K / 4); i += BS) {
        int r = i / (K / 4);
        int kq = i % (K / 4);
        int grow = r0 + r;
        float4 v = make_float4(0.f, 0.f, 0.f, 0.f);
        if (grow < n) v = ((const float4*)A)[(size_t)grow * (K / 4) + kq];
        ((float4*)(xs + r * KS))[kq] = v;
    }
    __syncthreads();

    int cg = tid % CG;
    int rt = tid / CG;
    const float4* xr0 = (const float4*)(xs + (rt * 4 + 0) * KS);
    const float4* xr1 = (const float4*)(xs + (rt * 4 + 1) * KS);
    const float4* xr2 = (const float4*)(xs + (rt * 4 + 2) * KS);
    const float4* xr3 = (const float4*)(xs + (rt * 4 + 3) * KS);

    float4 acc[4];
#pragma unroll
    for (int j = 0; j < 4; ++j) acc[j] = make_float4(0, 0, 0, 0);

#pragma unroll 2
    for (int kq = 0; kq < K / 4; ++kq) {
        float4 a0 = xr0[kq], a1 = xr1[kq], a2 = xr2[kq], a3 = xr3[kq];
        float4 w0 = ws4[(4 * kq + 0) * CG + cg];
        float4 w1 = ws4[(4 * kq + 1) * CG + cg];
        float4 w2 = ws4[(4 * kq + 2) * CG + cg];
        float4 w3 = ws4[(4 * kq + 3) * CG + cg];
#define FMA4(ac, a)                                                            \
        ac.x += a.x * w0.x + a.y * w1.x + a.z * w2.x + a.w * w3.x;             \
        ac.y += a.x * w0.y + a.y * w1.y + a.z * w2.y + a.w * w3.y;             \
        ac.z += a.x * w0.z + a.y * w1.z + a.z * w2.z + a.w * w3.z;             \
        ac.w += a.x * w0.w + a.y * w1.w + a.z * w2.w + a.w * w3.w;
        FMA4(acc[0], a0)
        FMA4(acc[1], a1)
        FMA4(acc[2], a2)
        FMA4(acc[3], a3)
#undef FMA4
    }

#pragma unroll
    for (int j = 0; j < 4; ++j) {
        int grow = r0 + rt * 4 + j;
        if (grow < n) {
            float dv = dinv[grow];
            uint2 o;
            o.x = pack_bf16x2(acc[j].x * dv, acc[j].y * dv);
            o.y = pack_bf16x2(acc[j].z * dv, acc[j].w * dv);
            ((uint2*)(G + (size_t)grow * (COLS / 2)))[cg] = o;
        }
    }
}

// out[node][c] = act( dinv[node] * (G[node][c] + sum_{s in CSR(node)} G[s][c]) + b[c] )
// G is bf16-packed; each lane covers 8 channels (one uint4). 8-deep gather MLP.
template <int C, bool RELU>
__global__ __launch_bounds__(BS) void agg_kernel(const unsigned* __restrict__ G,
                                                 const int* __restrict__ edge_off,
                                                 const int* __restrict__ cnt,
                                                 const int* __restrict__ src,
                                                 const float* __restrict__ dinv,
                                                 const float* __restrict__ bias,
                                                 float* __restrict__ out, int n) {
    constexpr int Gp = C / 8;          // uint4 lanes per node (8 bf16 each)
    constexpr int NPB = BS / Gp;       // nodes per block
    int lane = threadIdx.x % Gp;
    int li = threadIdx.x / Gp;
    int node = blockIdx.x * NPB + li;
    if (node >= n) return;

    const uint4* G4 = (const uint4*)G;
    float acc[8];
    {
        uint4 sv = G4[(size_t)node * Gp + lane];   // self-loop term
        acc[0] = bf_lo(sv.x); acc[1] = bf_hi(sv.x);
        acc[2] = bf_lo(sv.y); acc[3] = bf_hi(sv.y);
        acc[4] = bf_lo(sv.z); acc[5] = bf_hi(sv.z);
        acc[6] = bf_lo(sv.w); acc[7] = bf_hi(sv.w);
    }
    const int* sp = src + edge_off[node];
    int deg = cnt[node];

#define ACCUM(v)                                                               \
    acc[0] += bf_lo(v.x); acc[1] += bf_hi(v.x);                                \
    acc[2] += bf_lo(v.y); acc[3] += bf_hi(v.y);                                \
    acc[4] += bf_lo(v.z); acc[5] += bf_hi(v.z);                                \
    acc[6] += bf_lo(v.w); acc[7] += bf_hi(v.w);

    int i = 0;
    for (; i + 8 <= deg; i += 8) {
        int s0 = sp[i + 0], s1 = sp[i + 1], s2 = sp[i + 2], s3 = sp[i + 3];
        int s4 = sp[i + 4], s5 = sp[i + 5], s6 = sp[i + 6], s7 = sp[i + 7];
        uint4 v0 = G4[(size_t)s0 * Gp + lane];
        uint4 v1 = G4[(size_t)s1 * Gp + lane];
        uint4 v2 = G4[(size_t)s2 * Gp + lane];
        uint4 v3 = G4[(size_t)s3 * Gp + lane];
        uint4 v4 = G4[(size_t)s4 * Gp + lane];
        uint4 v5 = G4[(size_t)s5 * Gp + lane];
        uint4 v6 = G4[(size_t)s6 * Gp + lane];
        uint4 v7 = G4[(size_t)s7 * Gp + lane];
        ACCUM(v0) ACCUM(v1) ACCUM(v2) ACCUM(v3)
        ACCUM(v4) ACCUM(v5) ACCUM(v6) ACCUM(v7)
    }
    for (; i + 2 <= deg; i += 2) {
        int s0 = sp[i + 0], s1 = sp[i + 1];
        uint4 v0 = G4[(size_t)s0 * Gp + lane];
        uint4 v1 = G4[(size_t)s1 * Gp + lane];
        ACCUM(v0) ACCUM(v1)
    }
    if (i < deg) {
        uint4 v0 = G4[(size_t)sp[i] * Gp + lane];
        ACCUM(v0)
    }
#undef ACCUM

    float dv = dinv[node];
    const float4* b4 = (const float4*)bias;
    float4 bl = b4[2 * lane + 0], bh = b4[2 * lane + 1];
    float4 o0 = make_float4(acc[0] * dv + bl.x, acc[1] * dv + bl.y,
                            acc[2] * dv + bl.z, acc[3] * dv + bl.w);
    float4 o1 = make_float4(acc[4] * dv + bh.x, acc[5] * dv + bh.y,
                            acc[6] * dv + bh.z, acc[7] * dv + bh.w);
    if (RELU) {
        o0.x = fmaxf(o0.x, 0.f); o0.y = fmaxf(o0.y, 0.f);
        o0.z = fmaxf(o0.z, 0.f); o0.w = fmaxf(o0.w, 0.f);
        o1.x = fmaxf(o1.x, 0.f); o1.y = fmaxf(o1.y, 0.f);
        o1.z = fmaxf(o1.z, 0.f); o1.w = fmaxf(o1.w, 0.f);
    }
    float4* orow = (float4*)(out + (size_t)node * C);
    orow[2 * lane + 0] = o0;
    orow[2 * lane + 1] = o1;
}

extern "C" void kernel_launch(void* const* d_in, const int* in_sizes, int n_in,
                              void* d_out, int out_size, void* d_ws, size_t ws_size,
                              hipStream_t stream) {
    const float* x  = (const float*)d_in[0];
    const int*   ei = (const int*)d_in[1];      // [2, E] int32
    const float* W1 = (const float*)d_in[2];
    const float* b1 = (const float*)d_in[3];
    const float* W2 = (const float*)d_in[4];
    const float* b2 = (const float*)d_in[5];

    const int IN_C = 128, HID_C = 128;
    int n = in_sizes[0] / IN_C;
    int E = in_sizes[1] / 2;
    const int* row = ei;
    const int* col = ei + E;

    int NB = (n + BS - 1) / BS;

    char* w = (char*)d_ws;
    auto alloc = [&](size_t bytes) {
        void* p = (void*)w;
        w += (bytes + 255) & ~(size_t)255;
        return p;
    };
    int*      cnt    = (int*)alloc((size_t)n * 4);
    int*      off    = (int*)alloc((size_t)n * 4);
    int*      cursor = (int*)alloc((size_t)n * 4);
    int*      bsum   = (int*)alloc((size_t)NB * 4);
    int*      boff   = (int*)alloc((size_t)NB * 4);
    int*      src    = (int*)alloc((size_t)E * 4);
    float*    dinv   = (float*)alloc((size_t)n * 4);
    unsigned* g      = (unsigned*)alloc((size_t)n * HID_C * 2);  // bf16-packed
    float*    h1     = (float*)alloc((size_t)n * HID_C * 4);

    hipMemsetAsync(cnt, 0, (size_t)n * 4, stream);

    int gridE = (E + BS - 1) / BS;

    // degree + CSR build
    count_kernel<<<gridE, BS, 0, stream>>>(col, cnt, E);
    scan_block_kernel<<<NB, BS, 0, stream>>>(cnt, off, bsum, n);
    scan_bsum_kernel<<<1, 512, 0, stream>>>(bsum, boff, NB);
    add_off_dinv_kernel<<<NB, BS, 0, stream>>>(off, boff, cnt, cursor, dinv, n);
    scatter_kernel<<<gridE, BS, 0, stream>>>(row, col, cursor, src, E);

    // layer 1: g1 = bf16(dinv * (x @ W1)); h1 = relu(dinv*(self + gather) + b1)
    gemm_scale_kernel<128><<<(n + 31) / 32, BS, 0, stream>>>(x, W1, dinv, g, n);
    agg_kernel<128, true><<<(n + 15) / 16, BS, 0, stream>>>(g, off, cnt, src, dinv, b1, h1, n);

    // layer 2: g2 = bf16(dinv * (h1 @ W2)); out = dinv*(self + gather) + b2
    gemm_scale_kernel<64><<<(n + 63) / 64, BS, 0, stream>>>(h1, W2, dinv, g, n);
    agg_kernel<64, false><<<(n + 31) / 32, BS, 0, stream>>>(g, off, cnt, src, dinv, b2,
                                                            (float*)d_out, n);
}

// Round 6
// 428.058 us; speedup vs baseline: 1.3562x; 1.1674x over previous
//
#include <hip/hip_runtime.h>
#include <math.h>

// ---------------------------------------------------------------------------
// 2-layer GCN (PyG GCNConv semantics) on MI355X.
//   deg[c]  = #incoming edges + 1 (self loop); dinv = rsqrt(deg)
//   g       = bf16( dinv[n] * (X @ W) )     (GEMM + epilogue scale + pack)
//   out[c]  = dinv[c] * (g[c] + sum_{(r,c) in E} g[r]) + b   (CSR gather)
//   layer1: ReLU -> h1 (fp32); layer2: none, writes d_out (fp32).
// CSR built once per call; no float atomics anywhere.
// R6: rank trick merges count into the position-claim pass:
//     rank[i] = atomicAdd(cnt[c],1)  (counts AND claims slot, coalesced rank
//     write), then atomic-free placement src[off[c]+rank[i]] = row[i]
//     (off is 400KB = L2-resident, cheap; src write is the pricey random op,
//     done nontemporal to skip L2 line churn). One atomic pass instead of two.
// ---------------------------------------------------------------------------

#define BS 256

__device__ __forceinline__ unsigned pack_bf16x2(float a, float b) {
    unsigned ua = __float_as_uint(a);
    unsigned ub = __float_as_uint(b);
    ua = (ua + 0x7fffu + ((ua >> 16) & 1u)) >> 16;   // RTE
    ub = (ub + 0x7fffu + ((ub >> 16) & 1u)) >> 16;
    return ua | (ub << 16);
}

__device__ __forceinline__ float bf_lo(unsigned u) { return __uint_as_float(u << 16); }
__device__ __forceinline__ float bf_hi(unsigned u) { return __uint_as_float(u & 0xffff0000u); }

// rank[i] = old count of col[i]  (single atomic pass: count + slot claim)
__global__ __launch_bounds__(BS) void rank_kernel(const int* __restrict__ col,
                                                  int* __restrict__ cnt,
                                                  int* __restrict__ rank, int E) {
    int i = blockIdx.x * BS + threadIdx.x;
    if (i < E) rank[i] = atomicAdd(&cnt[col[i]], 1);
}

__global__ __launch_bounds__(BS) void scan_block_kernel(const int* __restrict__ cnt,
                                                        int* __restrict__ exc,
                                                        int* __restrict__ bsum, int N) {
    __shared__ int s[BS];
    int tid = threadIdx.x;
    int i = blockIdx.x * BS + tid;
    int v = (i < N) ? cnt[i] : 0;
    s[tid] = v;
    __syncthreads();
    for (int off = 1; off < BS; off <<= 1) {
        int t = (tid >= off) ? s[tid - off] : 0;
        __syncthreads();
        s[tid] += t;
        __syncthreads();
    }
    if (i < N) exc[i] = s[tid] - v;       // exclusive within block
    if (tid == BS - 1) bsum[blockIdx.x] = s[BS - 1];
}

__global__ __launch_bounds__(512) void scan_bsum_kernel(const int* __restrict__ bsum,
                                                        int* __restrict__ boff, int NB) {
    __shared__ int s[512];
    int tid = threadIdx.x;
    int v = (tid < NB) ? bsum[tid] : 0;
    s[tid] = v;
    __syncthreads();
    for (int off = 1; off < 512; off <<= 1) {
        int t = (tid >= off) ? s[tid - off] : 0;
        __syncthreads();
        s[tid] += t;
        __syncthreads();
    }
    if (tid < NB) boff[tid] = s[tid] - v; // exclusive across blocks
}

// exc += block offset; dinv = rsqrt(deg+1)
__global__ __launch_bounds__(BS) void add_off_dinv_kernel(int* __restrict__ exc,
                                                          const int* __restrict__ boff,
                                                          const int* __restrict__ cnt,
                                                          float* __restrict__ dinv, int N) {
    int i = blockIdx.x * BS + threadIdx.x;
    if (i < N) {
        exc[i] += boff[blockIdx.x];
        dinv[i] = rsqrtf((float)(cnt[i] + 1));
    }
}

// src[off[c] + rank[i]] = row[i] -- atomic-free placement.
__global__ __launch_bounds__(BS) void place_kernel(const int* __restrict__ row,
                                                   const int* __restrict__ col,
                                                   const int* __restrict__ rank,
                                                   const int* __restrict__ off,
                                                   int* __restrict__ src, int E) {
    int i = blockIdx.x * BS + threadIdx.x;
    if (i >= E) return;
    int p = off[col[i]] + rank[i];
    __builtin_nontemporal_store(row[i], &src[p]);
}

// G[n][COLS] (bf16, packed pairs) = bf16( dinv[n] * (A[n][128] @ W[128][COLS]) )
template <int COLS>
__global__ __launch_bounds__(BS) void gemm_scale_kernel(const float* __restrict__ A,
                                                        const float* __restrict__ W,
                                                        const float* __restrict__ dinv,
                                                        unsigned* __restrict__ G, int n) {
    constexpr int K = 128;
    constexpr int CG = COLS / 4;
    constexpr int RT = BS / CG;
    constexpr int ROWS = RT * 4;
    constexpr int KS = (COLS == 64) ? (K + 4) : K;   // xs row stride (floats)

    __shared__ float ws[K * COLS];
    __shared__ float xs[ROWS * KS];

    int tid = threadIdx.x;
    int r0 = blockIdx.x * ROWS;

    const float4* W4 = (const float4*)W;
    float4* ws4 = (float4*)ws;
    for (int i = tid; i < K * CG; i += BS) ws4[i] = W4[i];

    for (int i = tid; i < ROWS * (K / 4); i += BS) {
        int r = i / (K / 4);
        int kq = i % (K / 4);
        int grow = r0 + r;
        float4 v = make_float4(0.f, 0.f, 0.f, 0.f);
        if (grow < n) v = ((const float4*)A)[(size_t)grow * (K / 4) + kq];
        ((float4*)(xs + r * KS))[kq] = v;
    }
    __syncthreads();

    int cg = tid % CG;
    int rt = tid / CG;
    const float4* xr0 = (const float4*)(xs + (rt * 4 + 0) * KS);
    const float4* xr1 = (const float4*)(xs + (rt * 4 + 1) * KS);
    const float4* xr2 = (const float4*)(xs + (rt * 4 + 2) * KS);
    const float4* xr3 = (const float4*)(xs + (rt * 4 + 3) * KS);

    float4 acc[4];
#pragma unroll
    for (int j = 0; j < 4; ++j) acc[j] = make_float4(0, 0, 0, 0);

#pragma unroll 2
    for (int kq = 0; kq < K / 4; ++kq) {
        float4 a0 = xr0[kq], a1 = xr1[kq], a2 = xr2[kq], a3 = xr3[kq];
        float4 w0 = ws4[(4 * kq + 0) * CG + cg];
        float4 w1 = ws4[(4 * kq + 1) * CG + cg];
        float4 w2 = ws4[(4 * kq + 2) * CG + cg];
        float4 w3 = ws4[(4 * kq + 3) * CG + cg];
#define FMA4(ac, a)                                                            \
        ac.x += a.x * w0.x + a.y * w1.x + a.z * w2.x + a.w * w3.x;             \
        ac.y += a.x * w0.y + a.y * w1.y + a.z * w2.y + a.w * w3.y;             \
        ac.z += a.x * w0.z + a.y * w1.z + a.z * w2.z + a.w * w3.z;             \
        ac.w += a.x * w0.w + a.y * w1.w + a.z * w2.w + a.w * w3.w;
        FMA4(acc[0], a0)
        FMA4(acc[1], a1)
        FMA4(acc[2], a2)
        FMA4(acc[3], a3)
#undef FMA4
    }

#pragma unroll
    for (int j = 0; j < 4; ++j) {
        int grow = r0 + rt * 4 + j;
        if (grow < n) {
            float dv = dinv[grow];
            uint2 o;
            o.x = pack_bf16x2(acc[j].x * dv, acc[j].y * dv);
            o.y = pack_bf16x2(acc[j].z * dv, acc[j].w * dv);
            ((uint2*)(G + (size_t)grow * (COLS / 2)))[cg] = o;
        }
    }
}

// out[node][c] = act( dinv[node] * (G[node][c] + sum_{s in CSR(node)} G[s][c]) + b[c] )
// G is bf16-packed; each lane covers 8 channels (one uint4). 8-deep gather MLP.
template <int C, bool RELU>
__global__ __launch_bounds__(BS) void agg_kernel(const unsigned* __restrict__ G,
                                                 const int* __restrict__ edge_off,
                                                 const int* __restrict__ cnt,
                                                 const int* __restrict__ src,
                                                 const float* __restrict__ dinv,
                                                 const float* __restrict__ bias,
                                                 float* __restrict__ out, int n) {
    constexpr int Gp = C / 8;          // uint4 lanes per node (8 bf16 each)
    constexpr int NPB = BS / Gp;       // nodes per block
    int lane = threadIdx.x % Gp;
    int li = threadIdx.x / Gp;
    int node = blockIdx.x * NPB + li;
    if (node >= n) return;

    const uint4* G4 = (const uint4*)G;
    float acc[8];
    {
        uint4 sv = G4[(size_t)node * Gp + lane];   // self-loop term
        acc[0] = bf_lo(sv.x); acc[1] = bf_hi(sv.x);
        acc[2] = bf_lo(sv.y); acc[3] = bf_hi(sv.y);
        acc[4] = bf_lo(sv.z); acc[5] = bf_hi(sv.z);
        acc[6] = bf_lo(sv.w); acc[7] = bf_hi(sv.w);
    }
    const int* sp = src + edge_off[node];
    int deg = cnt[node];

#define ACCUM(v)                                                               \
    acc[0] += bf_lo(v.x); acc[1] += bf_hi(v.x);                                \
    acc[2] += bf_lo(v.y); acc[3] += bf_hi(v.y);                                \
    acc[4] += bf_lo(v.z); acc[5] += bf_hi(v.z);                                \
    acc[6] += bf_lo(v.w); acc[7] += bf_hi(v.w);

    int i = 0;
    for (; i + 8 <= deg; i += 8) {
        int s0 = sp[i + 0], s1 = sp[i + 1], s2 = sp[i + 2], s3 = sp[i + 3];
        int s4 = sp[i + 4], s5 = sp[i + 5], s6 = sp[i + 6], s7 = sp[i + 7];
        uint4 v0 = G4[(size_t)s0 * Gp + lane];
        uint4 v1 = G4[(size_t)s1 * Gp + lane];
        uint4 v2 = G4[(size_t)s2 * Gp + lane];
        uint4 v3 = G4[(size_t)s3 * Gp + lane];
        uint4 v4 = G4[(size_t)s4 * Gp + lane];
        uint4 v5 = G4[(size_t)s5 * Gp + lane];
        uint4 v6 = G4[(size_t)s6 * Gp + lane];
        uint4 v7 = G4[(size_t)s7 * Gp + lane];
        ACCUM(v0) ACCUM(v1) ACCUM(v2) ACCUM(v3)
        ACCUM(v4) ACCUM(v5) ACCUM(v6) ACCUM(v7)
    }
    for (; i + 2 <= deg; i += 2) {
        int s0 = sp[i + 0], s1 = sp[i + 1];
        uint4 v0 = G4[(size_t)s0 * Gp + lane];
        uint4 v1 = G4[(size_t)s1 * Gp + lane];
        ACCUM(v0) ACCUM(v1)
    }
    if (i < deg) {
        uint4 v0 = G4[(size_t)sp[i] * Gp + lane];
        ACCUM(v0)
    }
#undef ACCUM

    float dv = dinv[node];
    const float4* b4 = (const float4*)bias;
    float4 bl = b4[2 * lane + 0], bh = b4[2 * lane + 1];
    float4 o0 = make_float4(acc[0] * dv + bl.x, acc[1] * dv + bl.y,
                            acc[2] * dv + bl.z, acc[3] * dv + bl.w);
    float4 o1 = make_float4(acc[4] * dv + bh.x, acc[5] * dv + bh.y,
                            acc[6] * dv + bh.z, acc[7] * dv + bh.w);
    if (RELU) {
        o0.x = fmaxf(o0.x, 0.f); o0.y = fmaxf(o0.y, 0.f);
        o0.z = fmaxf(o0.z, 0.f); o0.w = fmaxf(o0.w, 0.f);
        o1.x = fmaxf(o1.x, 0.f); o1.y = fmaxf(o1.y, 0.f);
        o1.z = fmaxf(o1.z, 0.f); o1.w = fmaxf(o1.w, 0.f);
    }
    float4* orow = (float4*)(out + (size_t)node * C);
    orow[2 * lane + 0] = o0;
    orow[2 * lane + 1] = o1;
}

extern "C" void kernel_launch(void* const* d_in, const int* in_sizes, int n_in,
                              void* d_out, int out_size, void* d_ws, size_t ws_size,
                              hipStream_t stream) {
    const float* x  = (const float*)d_in[0];
    const int*   ei = (const int*)d_in[1];      // [2, E] int32
    const float* W1 = (const float*)d_in[2];
    const float* b1 = (const float*)d_in[3];
    const float* W2 = (const float*)d_in[4];
    const float* b2 = (const float*)d_in[5];

    const int IN_C = 128, HID_C = 128;
    int n = in_sizes[0] / IN_C;
    int E = in_sizes[1] / 2;
    const int* row = ei;
    const int* col = ei + E;

    int NB = (n + BS - 1) / BS;

    char* w = (char*)d_ws;
    auto alloc = [&](size_t bytes) {
        void* p = (void*)w;
        w += (bytes + 255) & ~(size_t)255;
        return p;
    };
    int*      cnt    = (int*)alloc((size_t)n * 4);
    int*      off    = (int*)alloc((size_t)n * 4);
    int*      bsum   = (int*)alloc((size_t)NB * 4);
    int*      boff   = (int*)alloc((size_t)NB * 4);
    int*      rank   = (int*)alloc((size_t)E * 4);
    int*      src    = (int*)alloc((size_t)E * 4);
    float*    dinv   = (float*)alloc((size_t)n * 4);
    unsigned* g      = (unsigned*)alloc((size_t)n * HID_C * 2);  // bf16-packed
    float*    h1     = (float*)alloc((size_t)n * HID_C * 4);

    hipMemsetAsync(cnt, 0, (size_t)n * 4, stream);

    int gridE = (E + BS - 1) / BS;

    // degree + CSR build (single atomic pass)
    rank_kernel<<<gridE, BS, 0, stream>>>(col, cnt, rank, E);
    scan_block_kernel<<<NB, BS, 0, stream>>>(cnt, off, bsum, n);
    scan_bsum_kernel<<<1, 512, 0, stream>>>(bsum, boff, NB);
    add_off_dinv_kernel<<<NB, BS, 0, stream>>>(off, boff, cnt, dinv, n);
    place_kernel<<<gridE, BS, 0, stream>>>(row, col, rank, off, src, E);

    // layer 1: g1 = bf16(dinv * (x @ W1)); h1 = relu(dinv*(self + gather) + b1)
    gemm_scale_kernel<128><<<(n + 31) / 32, BS, 0, stream>>>(x, W1, dinv, g, n);
    agg_kernel<128, true><<<(n + 15) / 16, BS, 0, stream>>>(g, off, cnt, src, dinv, b1, h1, n);

    // layer 2: g2 = bf16(dinv * (h1 @ W2)); out = dinv*(self + gather) + b2
    gemm_scale_kernel<64><<<(n + 63) / 64, BS, 0, stream>>>(h1, W2, dinv, g, n);
    agg_kernel<64, false><<<(n + 31) / 32, BS, 0, stream>>>(g, off, cnt, src, dinv, b2,
                                                            (float*)d_out, n);
}

// Round 7
// 342.751 us; speedup vs baseline: 1.6937x; 1.2489x over previous
//
#include <hip/hip_runtime.h>
#include <math.h>

// ---------------------------------------------------------------------------
// 2-layer GCN (PyG GCNConv semantics) on MI355X.
//   deg[c]  = #incoming edges + 1 (self loop); dinv = rsqrt(deg)
//   g       = bf16( dinv[n] * (X @ W) )     (MFMA GEMM + epilogue scale+pack)
//   out[c]  = dinv[c] * (g[c] + sum_{(r,c) in E} g[r]) + b   (CSR gather)
//   layer1: ReLU -> h1 (bf16); layer2: none, writes d_out (fp32).
// CSR built once per call (rank trick: one atomic pass); no float atomics.
// R7: GEMMs moved to v_mfma_f32_16x16x32_bf16 (fp32 path was LDS-occupancy-
//     capped at 19% and VALU-bound at ~50%). Transposed formulation:
//     D[ch][xrow] = W^T (A-op, LDS bf16, pad stride 136) * x (B-op, global).
//     Lane holds 4 consecutive channels of one x-row -> packed uint2 stores.
//     h1 stored bf16 (only layer-2 GEMM consumes it).
// ---------------------------------------------------------------------------

#define BS 256

typedef __attribute__((ext_vector_type(8))) short bf16x8;
typedef __attribute__((ext_vector_type(4))) float f32x4;

union FragU {
    bf16x8 v;
    unsigned u[4];
};

__device__ __forceinline__ unsigned pack_bf16x2(float a, float b) {
    unsigned ua = __float_as_uint(a);
    unsigned ub = __float_as_uint(b);
    ua = (ua + 0x7fffu + ((ua >> 16) & 1u)) >> 16;   // RTE
    ub = (ub + 0x7fffu + ((ub >> 16) & 1u)) >> 16;
    return ua | (ub << 16);
}

__device__ __forceinline__ ushort bf16_rte(float a) {
    unsigned ua = __float_as_uint(a);
    return (ushort)((ua + 0x7fffu + ((ua >> 16) & 1u)) >> 16);
}

__device__ __forceinline__ float bf_lo(unsigned u) { return __uint_as_float(u << 16); }
__device__ __forceinline__ float bf_hi(unsigned u) { return __uint_as_float(u & 0xffff0000u); }

// rank[i] = old count of col[i]  (single atomic pass: count + slot claim)
__global__ __launch_bounds__(BS) void rank_kernel(const int* __restrict__ col,
                                                  int* __restrict__ cnt,
                                                  int* __restrict__ rank, int E) {
    int i = blockIdx.x * BS + threadIdx.x;
    if (i < E) rank[i] = atomicAdd(&cnt[col[i]], 1);
}

__global__ __launch_bounds__(BS) void scan_block_kernel(const int* __restrict__ cnt,
                                                        int* __restrict__ exc,
                                                        int* __restrict__ bsum, int N) {
    __shared__ int s[BS];
    int tid = threadIdx.x;
    int i = blockIdx.x * BS + tid;
    int v = (i < N) ? cnt[i] : 0;
    s[tid] = v;
    __syncthreads();
    for (int off = 1; off < BS; off <<= 1) {
        int t = (tid >= off) ? s[tid - off] : 0;
        __syncthreads();
        s[tid] += t;
        __syncthreads();
    }
    if (i < N) exc[i] = s[tid] - v;       // exclusive within block
    if (tid == BS - 1) bsum[blockIdx.x] = s[BS - 1];
}

__global__ __launch_bounds__(512) void scan_bsum_kernel(const int* __restrict__ bsum,
                                                        int* __restrict__ boff, int NB) {
    __shared__ int s[512];
    int tid = threadIdx.x;
    int v = (tid < NB) ? bsum[tid] : 0;
    s[tid] = v;
    __syncthreads();
    for (int off = 1; off < 512; off <<= 1) {
        int t = (tid >= off) ? s[tid - off] : 0;
        __syncthreads();
        s[tid] += t;
        __syncthreads();
    }
    if (tid < NB) boff[tid] = s[tid] - v; // exclusive across blocks
}

// exc += block offset; dinv = rsqrt(deg+1)
__global__ __launch_bounds__(BS) void add_off_dinv_kernel(int* __restrict__ exc,
                                                          const int* __restrict__ boff,
                                                          const int* __restrict__ cnt,
                                                          float* __restrict__ dinv, int N) {
    int i = blockIdx.x * BS + threadIdx.x;
    if (i < N) {
        exc[i] += boff[blockIdx.x];
        dinv[i] = rsqrtf((float)(cnt[i] + 1));
    }
}

// src[off[c] + rank[i]] = row[i] -- atomic-free placement.
__global__ __launch_bounds__(BS) void place_kernel(const int* __restrict__ row,
                                                   const int* __restrict__ col,
                                                   const int* __restrict__ rank,
                                                   const int* __restrict__ off,
                                                   int* __restrict__ src, int E) {
    int i = blockIdx.x * BS + threadIdx.x;
    if (i >= E) return;
    int p = off[col[i]] + rank[i];
    __builtin_nontemporal_store(row[i], &src[p]);
}

// W^T-bf16 prep: wt1[n][k] = bf16(W1[k][n]) (128x128), wt2[n][k] = bf16(W2[k][n]) (64x128)
__global__ __launch_bounds__(BS) void wprep_kernel(const float* __restrict__ W1,
                                                   const float* __restrict__ W2,
                                                   ushort* __restrict__ wt1,
                                                   ushort* __restrict__ wt2) {
    int t = blockIdx.x * BS + threadIdx.x;
    if (t < 128 * 128) {
        int nn = t >> 7, k = t & 127;
        wt1[t] = bf16_rte(W1[k * 128 + nn]);
    }
    if (t < 64 * 128) {
        int nn = t >> 7, k = t & 127;
        wt2[t] = bf16_rte(W2[k * 64 + nn]);
    }
}

// G[m][ch] (bf16 packed) = bf16( dinv[m] * (A[m][128] @ W[128][NCH]) )
// MFMA 16x16x32, transposed: A-op = W^T (LDS, padded stride 136 shorts),
// B-op = A rows (global, fp32->bf16 in-reg if !IN_BF16).
// Block = 4 waves = 64 A-rows; wave w covers rows blockIdx*64 + w*16 .. +16.
template <int NCH, bool IN_BF16>
__global__ __launch_bounds__(BS) void gemm_mfma_kernel(const void* __restrict__ Ain,
                                                       const ushort* __restrict__ WT,
                                                       const float* __restrict__ dinv,
                                                       unsigned* __restrict__ G, int n) {
    constexpr int NT = NCH / 16;          // channel tiles
    constexpr int KP = 136;               // padded W^T row stride (shorts)
    __shared__ ushort wlds[NCH * KP];

    int tid = threadIdx.x;
    // stage W^T (NCH x 128 shorts) -> LDS, uint4 chunks (8 shorts), 16/row
    for (int c = tid; c < NCH * 16; c += BS) {
        int nr = c >> 4, q16 = c & 15;
        *(uint4*)(wlds + nr * KP + q16 * 8) = ((const uint4*)WT)[c];
    }
    __syncthreads();

    int lane = tid & 63, wv = tid >> 6;
    int ml = lane & 15, quad = lane >> 4;
    int m = blockIdx.x * 64 + wv * 16 + ml;

    // B-fragments: x[m][ks*32 + quad*8 .. +8] for ks=0..3
    FragU b[4];
    if (m < n) {
        if (IN_BF16) {
            const uint4* A = (const uint4*)Ain + (size_t)m * (NCH == 64 ? 16 : 16);
            // row = 128 bf16 = 16 uint4; frag at uint4 idx ks*4 + quad
#pragma unroll
            for (int ks = 0; ks < 4; ++ks) {
                uint4 t = ((const uint4*)Ain)[(size_t)m * 16 + ks * 4 + quad];
                b[ks].u[0] = t.x; b[ks].u[1] = t.y; b[ks].u[2] = t.z; b[ks].u[3] = t.w;
            }
        } else {
            const float4* A = (const float4*)Ain + (size_t)m * 32;
#pragma unroll
            for (int ks = 0; ks < 4; ++ks) {
                float4 p0 = A[ks * 8 + quad * 2];
                float4 p1 = A[ks * 8 + quad * 2 + 1];
                b[ks].u[0] = pack_bf16x2(p0.x, p0.y);
                b[ks].u[1] = pack_bf16x2(p0.z, p0.w);
                b[ks].u[2] = pack_bf16x2(p1.x, p1.y);
                b[ks].u[3] = pack_bf16x2(p1.z, p1.w);
            }
        }
    } else {
#pragma unroll
        for (int ks = 0; ks < 4; ++ks) {
            b[ks].u[0] = 0; b[ks].u[1] = 0; b[ks].u[2] = 0; b[ks].u[3] = 0;
        }
    }

    f32x4 acc[NT];
#pragma unroll
    for (int nt = 0; nt < NT; ++nt) {
        acc[nt][0] = 0.f; acc[nt][1] = 0.f; acc[nt][2] = 0.f; acc[nt][3] = 0.f;
    }

#pragma unroll
    for (int nt = 0; nt < NT; ++nt) {
#pragma unroll
        for (int ks = 0; ks < 4; ++ks) {
            bf16x8 a = *(const bf16x8*)(wlds + (nt * 16 + ml) * KP + ks * 32 + quad * 8);
            acc[nt] = __builtin_amdgcn_mfma_f32_16x16x32_bf16(a, b[ks].v, acc[nt], 0, 0, 0);
        }
    }

    if (m < n) {
        float dv = dinv[m];
        unsigned* grow = G + (size_t)m * (NCH / 2);
#pragma unroll
        for (int nt = 0; nt < NT; ++nt) {
            // lane's channels: nt*16 + quad*4 + reg (consecutive)
            uint2 o;
            o.x = pack_bf16x2(acc[nt][0] * dv, acc[nt][1] * dv);
            o.y = pack_bf16x2(acc[nt][2] * dv, acc[nt][3] * dv);
            *(uint2*)(grow + nt * 8 + quad * 2) = o;
        }
    }
}

// out[node][c] = act( dinv[node] * (G[node][c] + sum_{s in CSR(node)} G[s][c]) + b[c] )
// G bf16-packed; each lane covers 8 channels (one uint4). 8-deep gather MLP.
// OUT_BF16: pack output (h1 for layer-2 MFMA GEMM); else fp32 float4 (d_out).
template <int C, bool RELU, bool OUT_BF16>
__global__ __launch_bounds__(BS) void agg_kernel(const unsigned* __restrict__ G,
                                                 const int* __restrict__ edge_off,
                                                 const int* __restrict__ cnt,
                                                 const int* __restrict__ src,
                                                 const float* __restrict__ dinv,
                                                 const float* __restrict__ bias,
                                                 void* __restrict__ out, int n) {
    constexpr int Gp = C / 8;          // uint4 lanes per node (8 bf16 each)
    constexpr int NPB = BS / Gp;       // nodes per block
    int lane = threadIdx.x % Gp;
    int li = threadIdx.x / Gp;
    int node = blockIdx.x * NPB + li;
    if (node >= n) return;

    const uint4* G4 = (const uint4*)G;
    float acc[8];
    {
        uint4 sv = G4[(size_t)node * Gp + lane];   // self-loop term
        acc[0] = bf_lo(sv.x); acc[1] = bf_hi(sv.x);
        acc[2] = bf_lo(sv.y); acc[3] = bf_hi(sv.y);
        acc[4] = bf_lo(sv.z); acc[5] = bf_hi(sv.z);
        acc[6] = bf_lo(sv.w); acc[7] = bf_hi(sv.w);
    }
    const int* sp = src + edge_off[node];
    int deg = cnt[node];

#define ACCUM(v)                                                               \
    acc[0] += bf_lo(v.x); acc[1] += bf_hi(v.x);                                \
    acc[2] += bf_lo(v.y); acc[3] += bf_hi(v.y);                                \
    acc[4] += bf_lo(v.z); acc[5] += bf_hi(v.z);                                \
    acc[6] += bf_lo(v.w); acc[7] += bf_hi(v.w);

    int i = 0;
    for (; i + 8 <= deg; i += 8) {
        int s0 = sp[i + 0], s1 = sp[i + 1], s2 = sp[i + 2], s3 = sp[i + 3];
        int s4 = sp[i + 4], s5 = sp[i + 5], s6 = sp[i + 6], s7 = sp[i + 7];
        uint4 v0 = G4[(size_t)s0 * Gp + lane];
        uint4 v1 = G4[(size_t)s1 * Gp + lane];
        uint4 v2 = G4[(size_t)s2 * Gp + lane];
        uint4 v3 = G4[(size_t)s3 * Gp + lane];
        uint4 v4 = G4[(size_t)s4 * Gp + lane];
        uint4 v5 = G4[(size_t)s5 * Gp + lane];
        uint4 v6 = G4[(size_t)s6 * Gp + lane];
        uint4 v7 = G4[(size_t)s7 * Gp + lane];
        ACCUM(v0) ACCUM(v1) ACCUM(v2) ACCUM(v3)
        ACCUM(v4) ACCUM(v5) ACCUM(v6) ACCUM(v7)
    }
    for (; i + 2 <= deg; i += 2) {
        int s0 = sp[i + 0], s1 = sp[i + 1];
        uint4 v0 = G4[(size_t)s0 * Gp + lane];
        uint4 v1 = G4[(size_t)s1 * Gp + lane];
        ACCUM(v0) ACCUM(v1)
    }
    if (i < deg) {
        uint4 v0 = G4[(size_t)sp[i] * Gp + lane];
        ACCUM(v0)
    }
#undef ACCUM

    float dv = dinv[node];
    const float4* b4 = (const float4*)bias;
    float4 bl = b4[2 * lane + 0], bh = b4[2 * lane + 1];
    float o0x = acc[0] * dv + bl.x, o0y = acc[1] * dv + bl.y;
    float o0z = acc[2] * dv + bl.z, o0w = acc[3] * dv + bl.w;
    float o1x = acc[4] * dv + bh.x, o1y = acc[5] * dv + bh.y;
    float o1z = acc[6] * dv + bh.z, o1w = acc[7] * dv + bh.w;
    if (RELU) {
        o0x = fmaxf(o0x, 0.f); o0y = fmaxf(o0y, 0.f);
        o0z = fmaxf(o0z, 0.f); o0w = fmaxf(o0w, 0.f);
        o1x = fmaxf(o1x, 0.f); o1y = fmaxf(o1y, 0.f);
        o1z = fmaxf(o1z, 0.f); o1w = fmaxf(o1w, 0.f);
    }
    if (OUT_BF16) {
        uint4 ov;
        ov.x = pack_bf16x2(o0x, o0y);
        ov.y = pack_bf16x2(o0z, o0w);
        ov.z = pack_bf16x2(o1x, o1y);
        ov.w = pack_bf16x2(o1z, o1w);
        ((uint4*)out)[(size_t)node * Gp + lane] = ov;
    } else {
        float4* orow = (float4*)((float*)out + (size_t)node * C);
        orow[2 * lane + 0] = make_float4(o0x, o0y, o0z, o0w);
        orow[2 * lane + 1] = make_float4(o1x, o1y, o1z, o1w);
    }
}

extern "C" void kernel_launch(void* const* d_in, const int* in_sizes, int n_in,
                              void* d_out, int out_size, void* d_ws, size_t ws_size,
                              hipStream_t stream) {
    const float* x  = (const float*)d_in[0];
    const int*   ei = (const int*)d_in[1];      // [2, E] int32
    const float* W1 = (const float*)d_in[2];
    const float* b1 = (const float*)d_in[3];
    const float* W2 = (const float*)d_in[4];
    const float* b2 = (const float*)d_in[5];

    const int IN_C = 128, HID_C = 128;
    int n = in_sizes[0] / IN_C;
    int E = in_sizes[1] / 2;
    const int* row = ei;
    const int* col = ei + E;

    int NB = (n + BS - 1) / BS;

    char* w = (char*)d_ws;
    auto alloc = [&](size_t bytes) {
        void* p = (void*)w;
        w += (bytes + 255) & ~(size_t)255;
        return p;
    };
    int*      cnt    = (int*)alloc((size_t)n * 4);
    int*      off    = (int*)alloc((size_t)n * 4);
    int*      bsum   = (int*)alloc((size_t)NB * 4);
    int*      boff   = (int*)alloc((size_t)NB * 4);
    int*      rank   = (int*)alloc((size_t)E * 4);
    int*      src    = (int*)alloc((size_t)E * 4);
    float*    dinv   = (float*)alloc((size_t)n * 4);
    ushort*   wt1    = (ushort*)alloc(128 * 128 * 2);
    ushort*   wt2    = (ushort*)alloc(64 * 128 * 2);
    unsigned* g      = (unsigned*)alloc((size_t)n * HID_C * 2);  // bf16-packed
    unsigned* h1b    = (unsigned*)alloc((size_t)n * HID_C * 2);  // bf16-packed h1

    hipMemsetAsync(cnt, 0, (size_t)n * 4, stream);

    int gridE = (E + BS - 1) / BS;

    // W^T-bf16 prep (independent)
    wprep_kernel<<<64, BS, 0, stream>>>(W1, W2, wt1, wt2);

    // degree + CSR build (single atomic pass)
    rank_kernel<<<gridE, BS, 0, stream>>>(col, cnt, rank, E);
    scan_block_kernel<<<NB, BS, 0, stream>>>(cnt, off, bsum, n);
    scan_bsum_kernel<<<1, 512, 0, stream>>>(bsum, boff, NB);
    add_off_dinv_kernel<<<NB, BS, 0, stream>>>(off, boff, cnt, dinv, n);
    place_kernel<<<gridE, BS, 0, stream>>>(row, col, rank, off, src, E);

    int gridM = (n + 63) / 64;

    // layer 1: g = bf16(dinv * (x @ W1)); h1b = bf16(relu(dinv*(self+gather)+b1))
    gemm_mfma_kernel<128, false><<<gridM, BS, 0, stream>>>(x, wt1, dinv, g, n);
    agg_kernel<128, true, true><<<(n + 15) / 16, BS, 0, stream>>>(g, off, cnt, src,
                                                                  dinv, b1, h1b, n);

    // layer 2: g2 = bf16(dinv * (h1 @ W2)); out = dinv*(self+gather) + b2 (fp32)
    gemm_mfma_kernel<64, true><<<gridM, BS, 0, stream>>>(h1b, wt2, dinv, g, n);
    agg_kernel<64, false, false><<<(n + 31) / 32, BS, 0, stream>>>(g, off, cnt, src,
                                                                   dinv, b2, d_out, n);
}

// Round 8
// 338.267 us; speedup vs baseline: 1.7162x; 1.0133x over previous
//
#include <hip/hip_runtime.h>
#include <math.h>

// ---------------------------------------------------------------------------
// 2-layer GCN (PyG GCNConv semantics) on MI355X.
//   deg[c]  = #incoming edges + 1 (self loop); dinv = rsqrt(deg)
//   g       = bf16( dinv[n] * (X @ W) )     (MFMA GEMM + epilogue scale+pack)
//   out[c]  = dinv[c] * (g[c] + sum_{(r,c) in E} g[r]) + b   (CSR gather)
//   layer1: ReLU -> h1 (bf16); layer2: none, writes d_out (fp32).
// CSR built once per call; no float atomics.
// R8: split-counter rank -- 8 partition counter arrays (pi = blockIdx&7,
//     matches XCD round-robin) cut same-line atomic contention 8x (was 256
//     atomics/line on one 400KB array). Exact CSR: edge slot =
//     offp[pi][c] + local_rank, offp precomputed in the scan epilogue.
// ---------------------------------------------------------------------------

#define BS 256

typedef __attribute__((ext_vector_type(8))) short bf16x8;
typedef __attribute__((ext_vector_type(4))) float f32x4;

union FragU {
    bf16x8 v;
    unsigned u[4];
};

__device__ __forceinline__ unsigned pack_bf16x2(float a, float b) {
    unsigned ua = __float_as_uint(a);
    unsigned ub = __float_as_uint(b);
    ua = (ua + 0x7fffu + ((ua >> 16) & 1u)) >> 16;   // RTE
    ub = (ub + 0x7fffu + ((ub >> 16) & 1u)) >> 16;
    return ua | (ub << 16);
}

__device__ __forceinline__ ushort bf16_rte(float a) {
    unsigned ua = __float_as_uint(a);
    return (ushort)((ua + 0x7fffu + ((ua >> 16) & 1u)) >> 16);
}

__device__ __forceinline__ float bf_lo(unsigned u) { return __uint_as_float(u << 16); }
__device__ __forceinline__ float bf_hi(unsigned u) { return __uint_as_float(u & 0xffff0000u); }

// rank[i] = old partition-local count of col[i]; partition = blockIdx&7.
__global__ __launch_bounds__(BS) void rank8_kernel(const int* __restrict__ col,
                                                   int* __restrict__ cnt8,
                                                   int* __restrict__ rank, int E, int N) {
    int i = blockIdx.x * BS + threadIdx.x;
    if (i >= E) return;
    int pi = blockIdx.x & 7;
    rank[i] = atomicAdd(&cnt8[pi * N + col[i]], 1);
}

// block-exclusive scan of tot[i] = sum_p cnt8[p][i]; also writes tot (agg deg).
__global__ __launch_bounds__(BS) void scan_block8_kernel(const int* __restrict__ cnt8,
                                                         int* __restrict__ tot,
                                                         int* __restrict__ exc,
                                                         int* __restrict__ bsum, int N) {
    __shared__ int s[BS];
    int tid = threadIdx.x;
    int i = blockIdx.x * BS + tid;
    int v = 0;
    if (i < N) {
#pragma unroll
        for (int p = 0; p < 8; ++p) v += cnt8[p * N + i];
        tot[i] = v;
    }
    s[tid] = v;
    __syncthreads();
    for (int off = 1; off < BS; off <<= 1) {
        int t = (tid >= off) ? s[tid - off] : 0;
        __syncthreads();
        s[tid] += t;
        __syncthreads();
    }
    if (i < N) exc[i] = s[tid] - v;       // exclusive within block
    if (tid == BS - 1) bsum[blockIdx.x] = s[BS - 1];
}

__global__ __launch_bounds__(512) void scan_bsum_kernel(const int* __restrict__ bsum,
                                                        int* __restrict__ boff, int NB) {
    __shared__ int s[512];
    int tid = threadIdx.x;
    int v = (tid < NB) ? bsum[tid] : 0;
    s[tid] = v;
    __syncthreads();
    for (int off = 1; off < 512; off <<= 1) {
        int t = (tid >= off) ? s[tid - off] : 0;
        __syncthreads();
        s[tid] += t;
        __syncthreads();
    }
    if (tid < NB) boff[tid] = s[tid] - v; // exclusive across blocks
}

// exc -> final off; offp[p][c] = off[c] + prefix of cnt8 over partitions;
// dinv = rsqrt(deg+1).
__global__ __launch_bounds__(BS) void add_off_offp_dinv_kernel(int* __restrict__ exc,
                                                               const int* __restrict__ boff,
                                                               const int* __restrict__ cnt8,
                                                               int* __restrict__ offp,
                                                               float* __restrict__ dinv,
                                                               int N) {
    int i = blockIdx.x * BS + threadIdx.x;
    if (i >= N) return;
    int o = exc[i] + boff[blockIdx.x];
    exc[i] = o;
    int run = o;
#pragma unroll
    for (int p = 0; p < 8; ++p) {
        offp[p * N + i] = run;
        run += cnt8[p * N + i];
    }
    dinv[i] = rsqrtf((float)(run - o + 1));
}

// src[offp[pi][c] + rank[i]] = row[i] -- atomic-free placement.
__global__ __launch_bounds__(BS) void place_kernel(const int* __restrict__ row,
                                                   const int* __restrict__ col,
                                                   const int* __restrict__ rank,
                                                   const int* __restrict__ offp,
                                                   int* __restrict__ src, int E, int N) {
    int i = blockIdx.x * BS + threadIdx.x;
    if (i >= E) return;
    int pi = blockIdx.x & 7;
    int p = offp[pi * N + col[i]] + rank[i];
    __builtin_nontemporal_store(row[i], &src[p]);
}

// W^T-bf16 prep: wt1[n][k] = bf16(W1[k][n]) (128x128), wt2[n][k] = bf16(W2[k][n]) (64x128)
__global__ __launch_bounds__(BS) void wprep_kernel(const float* __restrict__ W1,
                                                   const float* __restrict__ W2,
                                                   ushort* __restrict__ wt1,
                                                   ushort* __restrict__ wt2) {
    int t = blockIdx.x * BS + threadIdx.x;
    if (t < 128 * 128) {
        int nn = t >> 7, k = t & 127;
        wt1[t] = bf16_rte(W1[k * 128 + nn]);
    }
    if (t < 64 * 128) {
        int nn = t >> 7, k = t & 127;
        wt2[t] = bf16_rte(W2[k * 64 + nn]);
    }
}

// G[m][ch] (bf16 packed) = bf16( dinv[m] * (A[m][128] @ W[128][NCH]) )
// MFMA 16x16x32, transposed: A-op = W^T (LDS, padded stride 136 shorts),
// B-op = A rows (global, fp32->bf16 in-reg if !IN_BF16).
template <int NCH, bool IN_BF16>
__global__ __launch_bounds__(BS) void gemm_mfma_kernel(const void* __restrict__ Ain,
                                                       const ushort* __restrict__ WT,
                                                       const float* __restrict__ dinv,
                                                       unsigned* __restrict__ G, int n) {
    constexpr int NT = NCH / 16;          // channel tiles
    constexpr int KP = 136;               // padded W^T row stride (shorts)
    __shared__ ushort wlds[NCH * KP];

    int tid = threadIdx.x;
    for (int c = tid; c < NCH * 16; c += BS) {
        int nr = c >> 4, q16 = c & 15;
        *(uint4*)(wlds + nr * KP + q16 * 8) = ((const uint4*)WT)[c];
    }
    __syncthreads();

    int lane = tid & 63, wv = tid >> 6;
    int ml = lane & 15, quad = lane >> 4;
    int m = blockIdx.x * 64 + wv * 16 + ml;

    FragU b[4];
    if (m < n) {
        if (IN_BF16) {
#pragma unroll
            for (int ks = 0; ks < 4; ++ks) {
                uint4 t = ((const uint4*)Ain)[(size_t)m * 16 + ks * 4 + quad];
                b[ks].u[0] = t.x; b[ks].u[1] = t.y; b[ks].u[2] = t.z; b[ks].u[3] = t.w;
            }
        } else {
            const float4* A = (const float4*)Ain + (size_t)m * 32;
#pragma unroll
            for (int ks = 0; ks < 4; ++ks) {
                float4 p0 = A[ks * 8 + quad * 2];
                float4 p1 = A[ks * 8 + quad * 2 + 1];
                b[ks].u[0] = pack_bf16x2(p0.x, p0.y);
                b[ks].u[1] = pack_bf16x2(p0.z, p0.w);
                b[ks].u[2] = pack_bf16x2(p1.x, p1.y);
                b[ks].u[3] = pack_bf16x2(p1.z, p1.w);
            }
        }
    } else {
#pragma unroll
        for (int ks = 0; ks < 4; ++ks) {
            b[ks].u[0] = 0; b[ks].u[1] = 0; b[ks].u[2] = 0; b[ks].u[3] = 0;
        }
    }

    f32x4 acc[NT];
#pragma unroll
    for (int nt = 0; nt < NT; ++nt) {
        acc[nt][0] = 0.f; acc[nt][1] = 0.f; acc[nt][2] = 0.f; acc[nt][3] = 0.f;
    }

#pragma unroll
    for (int nt = 0; nt < NT; ++nt) {
#pragma unroll
        for (int ks = 0; ks < 4; ++ks) {
            bf16x8 a = *(const bf16x8*)(wlds + (nt * 16 + ml) * KP + ks * 32 + quad * 8);
            acc[nt] = __builtin_amdgcn_mfma_f32_16x16x32_bf16(a, b[ks].v, acc[nt], 0, 0, 0);
        }
    }

    if (m < n) {
        float dv = dinv[m];
        unsigned* grow = G + (size_t)m * (NCH / 2);
#pragma unroll
        for (int nt = 0; nt < NT; ++nt) {
            uint2 o;
            o.x = pack_bf16x2(acc[nt][0] * dv, acc[nt][1] * dv);
            o.y = pack_bf16x2(acc[nt][2] * dv, acc[nt][3] * dv);
            *(uint2*)(grow + nt * 8 + quad * 2) = o;
        }
    }
}

// out[node][c] = act( dinv[node] * (G[node][c] + sum_{s in CSR(node)} G[s][c]) + b[c] )
// G bf16-packed; each lane covers 8 channels (one uint4). 8-deep gather MLP.
template <int C, bool RELU, bool OUT_BF16>
__global__ __launch_bounds__(BS) void agg_kernel(const unsigned* __restrict__ G,
                                                 const int* __restrict__ edge_off,
                                                 const int* __restrict__ cnt,
                                                 const int* __restrict__ src,
                                                 const float* __restrict__ dinv,
                                                 const float* __restrict__ bias,
                                                 void* __restrict__ out, int n) {
    constexpr int Gp = C / 8;          // uint4 lanes per node (8 bf16 each)
    constexpr int NPB = BS / Gp;       // nodes per block
    int lane = threadIdx.x % Gp;
    int li = threadIdx.x / Gp;
    int node = blockIdx.x * NPB + li;
    if (node >= n) return;

    const uint4* G4 = (const uint4*)G;
    float acc[8];
    {
        uint4 sv = G4[(size_t)node * Gp + lane];   // self-loop term
        acc[0] = bf_lo(sv.x); acc[1] = bf_hi(sv.x);
        acc[2] = bf_lo(sv.y); acc[3] = bf_hi(sv.y);
        acc[4] = bf_lo(sv.z); acc[5] = bf_hi(sv.z);
        acc[6] = bf_lo(sv.w); acc[7] = bf_hi(sv.w);
    }
    const int* sp = src + edge_off[node];
    int deg = cnt[node];

#define ACCUM(v)                                                               \
    acc[0] += bf_lo(v.x); acc[1] += bf_hi(v.x);                                \
    acc[2] += bf_lo(v.y); acc[3] += bf_hi(v.y);                                \
    acc[4] += bf_lo(v.z); acc[5] += bf_hi(v.z);                                \
    acc[6] += bf_lo(v.w); acc[7] += bf_hi(v.w);

    int i = 0;
    for (; i + 8 <= deg; i += 8) {
        int s0 = sp[i + 0], s1 = sp[i + 1], s2 = sp[i + 2], s3 = sp[i + 3];
        int s4 = sp[i + 4], s5 = sp[i + 5], s6 = sp[i + 6], s7 = sp[i + 7];
        uint4 v0 = G4[(size_t)s0 * Gp + lane];
        uint4 v1 = G4[(size_t)s1 * Gp + lane];
        uint4 v2 = G4[(size_t)s2 * Gp + lane];
        uint4 v3 = G4[(size_t)s3 * Gp + lane];
        uint4 v4 = G4[(size_t)s4 * Gp + lane];
        uint4 v5 = G4[(size_t)s5 * Gp + lane];
        uint4 v6 = G4[(size_t)s6 * Gp + lane];
        uint4 v7 = G4[(size_t)s7 * Gp + lane];
        ACCUM(v0) ACCUM(v1) ACCUM(v2) ACCUM(v3)
        ACCUM(v4) ACCUM(v5) ACCUM(v6) ACCUM(v7)
    }
    for (; i + 2 <= deg; i += 2) {
        int s0 = sp[i + 0], s1 = sp[i + 1];
        uint4 v0 = G4[(size_t)s0 * Gp + lane];
        uint4 v1 = G4[(size_t)s1 * Gp + lane];
        ACCUM(v0) ACCUM(v1)
    }
    if (i < deg) {
        uint4 v0 = G4[(size_t)sp[i] * Gp + lane];
        ACCUM(v0)
    }
#undef ACCUM

    float dv = dinv[node];
    const float4* b4 = (const float4*)bias;
    float4 bl = b4[2 * lane + 0], bh = b4[2 * lane + 1];
    float o0x = acc[0] * dv + bl.x, o0y = acc[1] * dv + bl.y;
    float o0z = acc[2] * dv + bl.z, o0w = acc[3] * dv + bl.w;
    float o1x = acc[4] * dv + bh.x, o1y = acc[5] * dv + bh.y;
    float o1z = acc[6] * dv + bh.z, o1w = acc[7] * dv + bh.w;
    if (RELU) {
        o0x = fmaxf(o0x, 0.f); o0y = fmaxf(o0y, 0.f);
        o0z = fmaxf(o0z, 0.f); o0w = fmaxf(o0w, 0.f);
        o1x = fmaxf(o1x, 0.f); o1y = fmaxf(o1y, 0.f);
        o1z = fmaxf(o1z, 0.f); o1w = fmaxf(o1w, 0.f);
    }
    if (OUT_BF16) {
        uint4 ov;
        ov.x = pack_bf16x2(o0x, o0y);
        ov.y = pack_bf16x2(o0z, o0w);
        ov.z = pack_bf16x2(o1x, o1y);
        ov.w = pack_bf16x2(o1z, o1w);
        ((uint4*)out)[(size_t)node * Gp + lane] = ov;
    } else {
        float4* orow = (float4*)((float*)out + (size_t)node * C);
        orow[2 * lane + 0] = make_float4(o0x, o0y, o0z, o0w);
        orow[2 * lane + 1] = make_float4(o1x, o1y, o1z, o1w);
    }
}

extern "C" void kernel_launch(void* const* d_in, const int* in_sizes, int n_in,
                              void* d_out, int out_size, void* d_ws, size_t ws_size,
                              hipStream_t stream) {
    const float* x  = (const float*)d_in[0];
    const int*   ei = (const int*)d_in[1];      // [2, E] int32
    const float* W1 = (const float*)d_in[2];
    const float* b1 = (const float*)d_in[3];
    const float* W2 = (const float*)d_in[4];
    const float* b2 = (const float*)d_in[5];

    const int IN_C = 128, HID_C = 128;
    int n = in_sizes[0] / IN_C;
    int E = in_sizes[1] / 2;
    const int* row = ei;
    const int* col = ei + E;

    int NB = (n + BS - 1) / BS;

    char* w = (char*)d_ws;
    auto alloc = [&](size_t bytes) {
        void* p = (void*)w;
        w += (bytes + 255) & ~(size_t)255;
        return p;
    };
    int*      cnt8   = (int*)alloc((size_t)n * 8 * 4);
    int*      tot    = (int*)alloc((size_t)n * 4);
    int*      off    = (int*)alloc((size_t)n * 4);
    int*      offp   = (int*)alloc((size_t)n * 8 * 4);
    int*      bsum   = (int*)alloc((size_t)NB * 4);
    int*      boff   = (int*)alloc((size_t)NB * 4);
    int*      rank   = (int*)alloc((size_t)E * 4);
    int*      src    = (int*)alloc((size_t)E * 4);
    float*    dinv   = (float*)alloc((size_t)n * 4);
    ushort*   wt1    = (ushort*)alloc(128 * 128 * 2);
    ushort*   wt2    = (ushort*)alloc(64 * 128 * 2);
    unsigned* g      = (unsigned*)alloc((size_t)n * HID_C * 2);  // bf16-packed
    unsigned* h1b    = (unsigned*)alloc((size_t)n * HID_C * 2);  // bf16-packed h1

    hipMemsetAsync(cnt8, 0, (size_t)n * 8 * 4, stream);

    int gridE = (E + BS - 1) / BS;

    // W^T-bf16 prep (independent)
    wprep_kernel<<<64, BS, 0, stream>>>(W1, W2, wt1, wt2);

    // degree + CSR build (split-counter single atomic pass)
    rank8_kernel<<<gridE, BS, 0, stream>>>(col, cnt8, rank, E, n);
    scan_block8_kernel<<<NB, BS, 0, stream>>>(cnt8, tot, off, bsum, n);
    scan_bsum_kernel<<<1, 512, 0, stream>>>(bsum, boff, NB);
    add_off_offp_dinv_kernel<<<NB, BS, 0, stream>>>(off, boff, cnt8, offp, dinv, n);
    place_kernel<<<gridE, BS, 0, stream>>>(row, col, rank, offp, src, E, n);

    int gridM = (n + 63) / 64;

    // layer 1: g = bf16(dinv * (x @ W1)); h1b = bf16(relu(dinv*(self+gather)+b1))
    gemm_mfma_kernel<128, false><<<gridM, BS, 0, stream>>>(x, wt1, dinv, g, n);
    agg_kernel<128, true, true><<<(n + 15) / 16, BS, 0, stream>>>(g, off, tot, src,
                                                                  dinv, b1, h1b, n);

    // layer 2: g2 = bf16(dinv * (h1 @ W2)); out = dinv*(self+gather) + b2 (fp32)
    gemm_mfma_kernel<64, true><<<gridM, BS, 0, stream>>>(h1b, wt2, dinv, g, n);
    agg_kernel<64, false, false><<<(n + 31) / 32, BS, 0, stream>>>(g, off, tot, src,
                                                                   dinv, b2, d_out, n);
}

// Round 9
// 267.187 us; speedup vs baseline: 2.1728x; 1.2660x over previous
//
#include <hip/hip_runtime.h>
#include <math.h>

// ---------------------------------------------------------------------------
// 2-layer GCN (PyG GCNConv semantics) on MI355X.
//   deg[c]  = #incoming edges + 1 (self loop); dinv = rsqrt(deg)
//   g       = bf16( dinv[n] * (X @ W) )     (MFMA GEMM + epilogue scale+pack)
//   out[c]  = dinv[c] * (g[c] + sum_{(r,c) in E} g[r]) + b   (CSR gather)
//   layer1: ReLU -> h1 (bf16); layer2: none, writes d_out (fp32).
// R9: CSR build via LDS-bucketed counting sort -- global atomics were the
//     limiter (25G/s issue-rate cap; split counters didn't move it, R8).
//     P1 LDS histogram (col>>9) -> scan countsT -> P2 bucket-grouped pairs
//     via LDS cursors -> P3 per-bucket LDS count/scan/place (off/deg/dinv/src).
//     Zero global atomics, zero memsets.
// Requires n <= 131072 (256-bucket LDS arrays in P1/P2); n = 100000 here.
// ---------------------------------------------------------------------------

#define BS 256
#define EPB 4096              // edges per P1/P2 block
#define BK_SHIFT 9            // 512 nodes per bucket

typedef __attribute__((ext_vector_type(8))) short bf16x8;
typedef __attribute__((ext_vector_type(4))) float f32x4;

union FragU {
    bf16x8 v;
    unsigned u[4];
};

__device__ __forceinline__ unsigned pack_bf16x2(float a, float b) {
    unsigned ua = __float_as_uint(a);
    unsigned ub = __float_as_uint(b);
    ua = (ua + 0x7fffu + ((ua >> 16) & 1u)) >> 16;   // RTE
    ub = (ub + 0x7fffu + ((ub >> 16) & 1u)) >> 16;
    return ua | (ub << 16);
}

__device__ __forceinline__ ushort bf16_rte(float a) {
    unsigned ua = __float_as_uint(a);
    return (ushort)((ua + 0x7fffu + ((ua >> 16) & 1u)) >> 16);
}

__device__ __forceinline__ float bf_lo(unsigned u) { return __uint_as_float(u << 16); }
__device__ __forceinline__ float bf_hi(unsigned u) { return __uint_as_float(u & 0xffff0000u); }

// P1: per-block LDS histogram over coarse buckets (col >> BK_SHIFT).
__global__ __launch_bounds__(BS) void p1_hist_kernel(const int* __restrict__ col,
                                                     int* __restrict__ countsT,
                                                     int E, int NBUCK, int NBLK) {
    __shared__ int h[256];
    int tid = threadIdx.x;
    h[tid] = 0;
    __syncthreads();
    int e0 = blockIdx.x * EPB;
    int e1 = min(e0 + EPB, E);
    for (int i = e0 + tid; i < e1; i += BS) atomicAdd(&h[col[i] >> BK_SHIFT], 1);
    __syncthreads();
    for (int b = tid; b < NBUCK; b += BS) countsT[b * NBLK + blockIdx.x] = h[b];
}

// generic block-exclusive scan (also used for countsT)
__global__ __launch_bounds__(BS) void scan_block_kernel(const int* __restrict__ in,
                                                        int* __restrict__ exc,
                                                        int* __restrict__ bsum, int N) {
    __shared__ int s[BS];
    int tid = threadIdx.x;
    int i = blockIdx.x * BS + tid;
    int v = (i < N) ? in[i] : 0;
    s[tid] = v;
    __syncthreads();
    for (int off = 1; off < BS; off <<= 1) {
        int t = (tid >= off) ? s[tid - off] : 0;
        __syncthreads();
        s[tid] += t;
        __syncthreads();
    }
    if (i < N) exc[i] = s[tid] - v;
    if (tid == BS - 1) bsum[blockIdx.x] = s[BS - 1];
}

__global__ __launch_bounds__(512) void scan_bsum_kernel(const int* __restrict__ bsum,
                                                        int* __restrict__ boff, int NB) {
    __shared__ int s[512];
    int tid = threadIdx.x;
    int v = (tid < NB) ? bsum[tid] : 0;
    s[tid] = v;
    __syncthreads();
    for (int off = 1; off < 512; off <<= 1) {
        int t = (tid >= off) ? s[tid - off] : 0;
        __syncthreads();
        s[tid] += t;
        __syncthreads();
    }
    if (tid < NB) boff[tid] = s[tid] - v;
}

__global__ __launch_bounds__(BS) void add_off_kernel(int* __restrict__ exc,
                                                     const int* __restrict__ boff, int N) {
    int i = blockIdx.x * BS + threadIdx.x;
    if (i < N) exc[i] += boff[blockIdx.x];
}

// P2: scatter edges into bucket-grouped pairs via LDS cursors.
__global__ __launch_bounds__(BS) void p2_scatter_kernel(const int* __restrict__ row,
                                                        const int* __restrict__ col,
                                                        const int* __restrict__ baseT,
                                                        uint2* __restrict__ pairs,
                                                        int E, int NBUCK, int NBLK) {
    __shared__ int cur[256];
    int tid = threadIdx.x;
    for (int b = tid; b < NBUCK; b += BS) cur[b] = baseT[b * NBLK + blockIdx.x];
    __syncthreads();
    int e0 = blockIdx.x * EPB;
    int e1 = min(e0 + EPB, E);
    for (int i = e0 + tid; i < e1; i += BS) {
        int c = col[i];
        int r = row[i];
        int pos = atomicAdd(&cur[c >> BK_SHIFT], 1);
        pairs[pos] = make_uint2((unsigned)r, (unsigned)c);
    }
}

// P3: per-bucket (512 nodes) LDS count + scan + place. Writes off/deg/dinv/src.
__global__ __launch_bounds__(BS) void p3_build_kernel(const uint2* __restrict__ pairs,
                                                      const int* __restrict__ baseT,
                                                      int* __restrict__ off_g,
                                                      int* __restrict__ deg_g,
                                                      float* __restrict__ dinv,
                                                      int* __restrict__ src,
                                                      int E, int n, int NBUCK, int NBLK) {
    __shared__ int cnt[512];
    __shared__ int scn[512];
    __shared__ int a256[256];
    int tid = threadIdx.x;
    int b = blockIdx.x;
    int s = baseT[b * NBLK];
    int eEnd = (b == NBUCK - 1) ? E : baseT[(b + 1) * NBLK];

    cnt[tid] = 0;
    cnt[tid + 256] = 0;
    __syncthreads();
    for (int i = s + tid; i < eEnd; i += BS) {
        uint2 p = pairs[i];
        atomicAdd(&cnt[p.y & 511], 1);
    }
    __syncthreads();
    int pairsum = cnt[2 * tid] + cnt[2 * tid + 1];
    a256[tid] = pairsum;
    __syncthreads();
    for (int off = 1; off < 256; off <<= 1) {
        int t = (tid >= off) ? a256[tid - off] : 0;
        __syncthreads();
        a256[tid] += t;
        __syncthreads();
    }
    int exc = a256[tid] - pairsum;
    scn[2 * tid] = exc;
    scn[2 * tid + 1] = exc + cnt[2 * tid];
    __syncthreads();
#pragma unroll
    for (int l = tid; l < 512; l += BS) {
        int node = (b << BK_SHIFT) + l;
        if (node < n) {
            off_g[node] = s + scn[l];
            deg_g[node] = cnt[l];
            dinv[node] = rsqrtf((float)(cnt[l] + 1));
        }
    }
    __syncthreads();
#pragma unroll
    for (int l = tid; l < 512; l += BS) scn[l] += s;   // cursors (global slots)
    __syncthreads();
    for (int i = s + tid; i < eEnd; i += BS) {
        uint2 p = pairs[i];
        int pos = atomicAdd(&scn[p.y & 511], 1);
        src[pos] = (int)p.x;
    }
}

// W^T-bf16 prep: wt1[n][k] = bf16(W1[k][n]) (128x128), wt2[n][k] = bf16(W2[k][n]) (64x128)
__global__ __launch_bounds__(BS) void wprep_kernel(const float* __restrict__ W1,
                                                   const float* __restrict__ W2,
                                                   ushort* __restrict__ wt1,
                                                   ushort* __restrict__ wt2) {
    int t = blockIdx.x * BS + threadIdx.x;
    if (t < 128 * 128) {
        int nn = t >> 7, k = t & 127;
        wt1[t] = bf16_rte(W1[k * 128 + nn]);
    }
    if (t < 64 * 128) {
        int nn = t >> 7, k = t & 127;
        wt2[t] = bf16_rte(W2[k * 64 + nn]);
    }
}

// G[m][ch] (bf16 packed) = bf16( dinv[m] * (A[m][128] @ W[128][NCH]) )
// MFMA 16x16x32, transposed: A-op = W^T (LDS, padded stride 136 shorts),
// B-op = A rows (global, fp32->bf16 in-reg if !IN_BF16).
template <int NCH, bool IN_BF16>
__global__ __launch_bounds__(BS) void gemm_mfma_kernel(const void* __restrict__ Ain,
                                                       const ushort* __restrict__ WT,
                                                       const float* __restrict__ dinv,
                                                       unsigned* __restrict__ G, int n) {
    constexpr int NT = NCH / 16;          // channel tiles
    constexpr int KP = 136;               // padded W^T row stride (shorts)
    __shared__ ushort wlds[NCH * KP];

    int tid = threadIdx.x;
    for (int c = tid; c < NCH * 16; c += BS) {
        int nr = c >> 4, q16 = c & 15;
        *(uint4*)(wlds + nr * KP + q16 * 8) = ((const uint4*)WT)[c];
    }
    __syncthreads();

    int lane = tid & 63, wv = tid >> 6;
    int ml = lane & 15, quad = lane >> 4;
    int m = blockIdx.x * 64 + wv * 16 + ml;

    FragU b[4];
    if (m < n) {
        if (IN_BF16) {
#pragma unroll
            for (int ks = 0; ks < 4; ++ks) {
                uint4 t = ((const uint4*)Ain)[(size_t)m * 16 + ks * 4 + quad];
                b[ks].u[0] = t.x; b[ks].u[1] = t.y; b[ks].u[2] = t.z; b[ks].u[3] = t.w;
            }
        } else {
            const float4* A = (const float4*)Ain + (size_t)m * 32;
#pragma unroll
            for (int ks = 0; ks < 4; ++ks) {
                float4 p0 = A[ks * 8 + quad * 2];
                float4 p1 = A[ks * 8 + quad * 2 + 1];
                b[ks].u[0] = pack_bf16x2(p0.x, p0.y);
                b[ks].u[1] = pack_bf16x2(p0.z, p0.w);
                b[ks].u[2] = pack_bf16x2(p1.x, p1.y);
                b[ks].u[3] = pack_bf16x2(p1.z, p1.w);
            }
        }
    } else {
#pragma unroll
        for (int ks = 0; ks < 4; ++ks) {
            b[ks].u[0] = 0; b[ks].u[1] = 0; b[ks].u[2] = 0; b[ks].u[3] = 0;
        }
    }

    f32x4 acc[NT];
#pragma unroll
    for (int nt = 0; nt < NT; ++nt) {
        acc[nt][0] = 0.f; acc[nt][1] = 0.f; acc[nt][2] = 0.f; acc[nt][3] = 0.f;
    }

#pragma unroll
    for (int nt = 0; nt < NT; ++nt) {
#pragma unroll
        for (int ks = 0; ks < 4; ++ks) {
            bf16x8 a = *(const bf16x8*)(wlds + (nt * 16 + ml) * KP + ks * 32 + quad * 8);
            acc[nt] = __builtin_amdgcn_mfma_f32_16x16x32_bf16(a, b[ks].v, acc[nt], 0, 0, 0);
        }
    }

    if (m < n) {
        float dv = dinv[m];
        unsigned* grow = G + (size_t)m * (NCH / 2);
#pragma unroll
        for (int nt = 0; nt < NT; ++nt) {
            uint2 o;
            o.x = pack_bf16x2(acc[nt][0] * dv, acc[nt][1] * dv);
            o.y = pack_bf16x2(acc[nt][2] * dv, acc[nt][3] * dv);
            *(uint2*)(grow + nt * 8 + quad * 2) = o;
        }
    }
}

// out[node][c] = act( dinv[node] * (G[node][c] + sum_{s in CSR(node)} G[s][c]) + b[c] )
// G bf16-packed; each lane covers 8 channels (one uint4). 8-deep gather MLP.
template <int C, bool RELU, bool OUT_BF16>
__global__ __launch_bounds__(BS) void agg_kernel(const unsigned* __restrict__ G,
                                                 const int* __restrict__ edge_off,
                                                 const int* __restrict__ cnt,
                                                 const int* __restrict__ src,
                                                 const float* __restrict__ dinv,
                                                 const float* __restrict__ bias,
                                                 void* __restrict__ out, int n) {
    constexpr int Gp = C / 8;          // uint4 lanes per node (8 bf16 each)
    constexpr int NPB = BS / Gp;       // nodes per block
    int lane = threadIdx.x % Gp;
    int li = threadIdx.x / Gp;
    int node = blockIdx.x * NPB + li;
    if (node >= n) return;

    const uint4* G4 = (const uint4*)G;
    float acc[8];
    {
        uint4 sv = G4[(size_t)node * Gp + lane];   // self-loop term
        acc[0] = bf_lo(sv.x); acc[1] = bf_hi(sv.x);
        acc[2] = bf_lo(sv.y); acc[3] = bf_hi(sv.y);
        acc[4] = bf_lo(sv.z); acc[5] = bf_hi(sv.z);
        acc[6] = bf_lo(sv.w); acc[7] = bf_hi(sv.w);
    }
    const int* sp = src + edge_off[node];
    int deg = cnt[node];

#define ACCUM(v)                                                               \
    acc[0] += bf_lo(v.x); acc[1] += bf_hi(v.x);                                \
    acc[2] += bf_lo(v.y); acc[3] += bf_hi(v.y);                                \
    acc[4] += bf_lo(v.z); acc[5] += bf_hi(v.z);                                \
    acc[6] += bf_lo(v.w); acc[7] += bf_hi(v.w);

    int i = 0;
    for (; i + 8 <= deg; i += 8) {
        int s0 = sp[i + 0], s1 = sp[i + 1], s2 = sp[i + 2], s3 = sp[i + 3];
        int s4 = sp[i + 4], s5 = sp[i + 5], s6 = sp[i + 6], s7 = sp[i + 7];
        uint4 v0 = G4[(size_t)s0 * Gp + lane];
        uint4 v1 = G4[(size_t)s1 * Gp + lane];
        uint4 v2 = G4[(size_t)s2 * Gp + lane];
        uint4 v3 = G4[(size_t)s3 * Gp + lane];
        uint4 v4 = G4[(size_t)s4 * Gp + lane];
        uint4 v5 = G4[(size_t)s5 * Gp + lane];
        uint4 v6 = G4[(size_t)s6 * Gp + lane];
        uint4 v7 = G4[(size_t)s7 * Gp + lane];
        ACCUM(v0) ACCUM(v1) ACCUM(v2) ACCUM(v3)
        ACCUM(v4) ACCUM(v5) ACCUM(v6) ACCUM(v7)
    }
    for (; i + 2 <= deg; i += 2) {
        int s0 = sp[i + 0], s1 = sp[i + 1];
        uint4 v0 = G4[(size_t)s0 * Gp + lane];
        uint4 v1 = G4[(size_t)s1 * Gp + lane];
        ACCUM(v0) ACCUM(v1)
    }
    if (i < deg) {
        uint4 v0 = G4[(size_t)sp[i] * Gp + lane];
        ACCUM(v0)
    }
#undef ACCUM

    float dv = dinv[node];
    const float4* b4 = (const float4*)bias;
    float4 bl = b4[2 * lane + 0], bh = b4[2 * lane + 1];
    float o0x = acc[0] * dv + bl.x, o0y = acc[1] * dv + bl.y;
    float o0z = acc[2] * dv + bl.z, o0w = acc[3] * dv + bl.w;
    float o1x = acc[4] * dv + bh.x, o1y = acc[5] * dv + bh.y;
    float o1z = acc[6] * dv + bh.z, o1w = acc[7] * dv + bh.w;
    if (RELU) {
        o0x = fmaxf(o0x, 0.f); o0y = fmaxf(o0y, 0.f);
        o0z = fmaxf(o0z, 0.f); o0w = fmaxf(o0w, 0.f);
        o1x = fmaxf(o1x, 0.f); o1y = fmaxf(o1y, 0.f);
        o1z = fmaxf(o1z, 0.f); o1w = fmaxf(o1w, 0.f);
    }
    if (OUT_BF16) {
        uint4 ov;
        ov.x = pack_bf16x2(o0x, o0y);
        ov.y = pack_bf16x2(o0z, o0w);
        ov.z = pack_bf16x2(o1x, o1y);
        ov.w = pack_bf16x2(o1z, o1w);
        ((uint4*)out)[(size_t)node * Gp + lane] = ov;
    } else {
        float4* orow = (float4*)((float*)out + (size_t)node * C);
        orow[2 * lane + 0] = make_float4(o0x, o0y, o0z, o0w);
        orow[2 * lane + 1] = make_float4(o1x, o1y, o1z, o1w);
    }
}

extern "C" void kernel_launch(void* const* d_in, const int* in_sizes, int n_in,
                              void* d_out, int out_size, void* d_ws, size_t ws_size,
                              hipStream_t stream) {
    const float* x  = (const float*)d_in[0];
    const int*   ei = (const int*)d_in[1];      // [2, E] int32
    const float* W1 = (const float*)d_in[2];
    const float* b1 = (const float*)d_in[3];
    const float* W2 = (const float*)d_in[4];
    const float* b2 = (const float*)d_in[5];

    const int IN_C = 128, HID_C = 128;
    int n = in_sizes[0] / IN_C;
    int E = in_sizes[1] / 2;
    const int* row = ei;
    const int* col = ei + E;

    int NBUCK = (n + 511) >> BK_SHIFT;          // coarse buckets (<=256 for n<=128k)
    int NBLK = (E + EPB - 1) / EPB;             // P1/P2 blocks
    int M = NBUCK * NBLK;                       // countsT entries
    int NBS = (M + BS - 1) / BS;                // scan blocks (<=512)

    char* w = (char*)d_ws;
    auto alloc = [&](size_t bytes) {
        void* p = (void*)w;
        w += (bytes + 255) & ~(size_t)255;
        return p;
    };
    int*      countsT = (int*)alloc((size_t)M * 4);
    int*      baseT   = (int*)alloc((size_t)M * 4);
    int*      bsum    = (int*)alloc((size_t)NBS * 4);
    int*      boff    = (int*)alloc((size_t)NBS * 4);
    uint2*    pairs   = (uint2*)alloc((size_t)E * 8);
    int*      src     = (int*)alloc((size_t)E * 4);
    int*      off     = (int*)alloc((size_t)n * 4);
    int*      deg     = (int*)alloc((size_t)n * 4);
    float*    dinv    = (float*)alloc((size_t)n * 4);
    ushort*   wt1     = (ushort*)alloc(128 * 128 * 2);
    ushort*   wt2     = (ushort*)alloc(64 * 128 * 2);
    unsigned* g       = (unsigned*)alloc((size_t)n * HID_C * 2);  // bf16-packed
    unsigned* h1b     = (unsigned*)alloc((size_t)n * HID_C * 2);  // bf16-packed h1

    // W^T-bf16 prep (independent)
    wprep_kernel<<<64, BS, 0, stream>>>(W1, W2, wt1, wt2);

    // CSR build: LDS-bucketed counting sort (no global atomics)
    p1_hist_kernel<<<NBLK, BS, 0, stream>>>(col, countsT, E, NBUCK, NBLK);
    scan_block_kernel<<<NBS, BS, 0, stream>>>(countsT, baseT, bsum, M);
    scan_bsum_kernel<<<1, 512, 0, stream>>>(bsum, boff, NBS);
    add_off_kernel<<<NBS, BS, 0, stream>>>(baseT, boff, M);
    p2_scatter_kernel<<<NBLK, BS, 0, stream>>>(row, col, baseT, pairs, E, NBUCK, NBLK);
    p3_build_kernel<<<NBUCK, BS, 0, stream>>>(pairs, baseT, off, deg, dinv, src,
                                              E, n, NBUCK, NBLK);

    int gridM = (n + 63) / 64;

    // layer 1: g = bf16(dinv * (x @ W1)); h1b = bf16(relu(dinv*(self+gather)+b1))
    gemm_mfma_kernel<128, false><<<gridM, BS, 0, stream>>>(x, wt1, dinv, g, n);
    agg_kernel<128, true, true><<<(n + 15) / 16, BS, 0, stream>>>(g, off, deg, src,
                                                                  dinv, b1, h1b, n);

    // layer 2: g2 = bf16(dinv * (h1 @ W2)); out = dinv*(self+gather) + b2 (fp32)
    gemm_mfma_kernel<64, true><<<gridM, BS, 0, stream>>>(h1b, wt2, dinv, g, n);
    agg_kernel<64, false, false><<<(n + 31) / 32, BS, 0, stream>>>(g, off, deg, src,
                                                                   dinv, b2, d_out, n);
}